// Round 2
// baseline (532.963 us; speedup 1.0000x reference)
//
#include <hip/hip_runtime.h>
#include <hip/hip_bf16.h>
#include <math.h>
#include <stdint.h>

typedef unsigned short u16;

__device__ __forceinline__ u16 f2bf(float f) {
    uint32_t u = __float_as_uint(f);
    u += 0x7fff + ((u >> 16) & 1);   // round-to-nearest-even
    return (u16)(u >> 16);
}
__device__ __forceinline__ float bf2f(u16 b) {
    return __uint_as_float((uint32_t)b << 16);
}

// ---------------- degree / norm ----------------
__global__ void k_init_deg(int* __restrict__ deg, int n) {
    int i = blockIdx.x * blockDim.x + threadIdx.x;
    if (i < n) deg[i] = 1;                    // self-loop
}

__global__ void k_hist(const int* __restrict__ col, int* __restrict__ deg, int E, int n) {
    int e = blockIdx.x * blockDim.x + threadIdx.x;
    if (e < E) {
        int c = col[e];
        if ((unsigned)c < (unsigned)n) atomicAdd(&deg[c], 1);
    }
}

__global__ void k_dinv(const int* __restrict__ deg, float* __restrict__ dinv, int n) {
    int i = blockIdx.x * blockDim.x + threadIdx.x;
    if (i < n) dinv[i] = rsqrtf((float)deg[i]);   // deg >= 1 always (self-loop)
}

// ---------------- exclusive scan (3 kernels) ----------------
__global__ void k_scan1(const int* __restrict__ cnt, int* __restrict__ excl,
                        int* __restrict__ part, int n) {
    __shared__ int sh[1024];
    int i = blockIdx.x * 1024 + threadIdx.x;
    int v = (i < n) ? cnt[i] : 0;
    sh[threadIdx.x] = v;
    __syncthreads();
    for (int d = 1; d < 1024; d <<= 1) {
        int t = (threadIdx.x >= (unsigned)d) ? sh[threadIdx.x - d] : 0;
        __syncthreads();
        sh[threadIdx.x] += t;
        __syncthreads();
    }
    if (i < n) excl[i] = sh[threadIdx.x] - v;
    if (threadIdx.x == 1023) part[blockIdx.x] = sh[1023];
}

__global__ void k_scan2(int* __restrict__ part, int nb) {
    __shared__ int sh[1024];
    int v = ((int)threadIdx.x < nb) ? part[threadIdx.x] : 0;
    sh[threadIdx.x] = v;
    __syncthreads();
    for (int d = 1; d < 1024; d <<= 1) {
        int t = (threadIdx.x >= (unsigned)d) ? sh[threadIdx.x - d] : 0;
        __syncthreads();
        sh[threadIdx.x] += t;
        __syncthreads();
    }
    if ((int)threadIdx.x < nb) part[threadIdx.x] = sh[threadIdx.x] - v;  // exclusive
    if (threadIdx.x == 0) part[nb] = sh[1023];                            // total
}

__global__ void k_scan3(int* __restrict__ off, int* __restrict__ cursor,
                        const int* __restrict__ part, int n) {
    int i = blockIdx.x * blockDim.x + threadIdx.x;
    if (i < n) {
        int o = off[i] + part[i >> 10];
        off[i] = o;
        cursor[i] = o;
    } else if (i == n) {
        off[n] = part[(n + 1023) >> 10];
    }
}

// ---------------- CSR fill (counting-sort scatter) ----------------
__global__ void k_fill(const int* __restrict__ ei, const float* __restrict__ dinv,
                       int* __restrict__ cursor, int* __restrict__ csrs,
                       float* __restrict__ csrw, int E, int n) {
    int i = blockIdx.x * blockDim.x + threadIdx.x;
    if (i < E) {
        int r = ei[i], c = ei[E + i];
        if ((unsigned)r < (unsigned)n && (unsigned)c < (unsigned)n) {
            float w = dinv[r] * dinv[c];
            int p = atomicAdd(&cursor[c], 1);
            csrs[p] = r;
            csrw[p] = w;
        }
    } else if (i < E + n) {
        int c = i - E;
        float d = dinv[c];
        int p = atomicAdd(&cursor[c], 1);
        csrs[p] = c;
        csrw[p] = d * d;
    }
}

// ---------------- GEMM1: h = x @ W1  ([N,256]@[256,128]) -> bf16 ----------------
__global__ __launch_bounds__(256) void k_gemm1(const float* __restrict__ x,
                                               const float* __restrict__ w1,
                                               u16* __restrict__ hbf, int n) {
    __shared__ float xs[16][68];    // [k][row], pad 68 (17 quads, stride 1 mod 8)
    __shared__ float ws[16][128];   // [k][col]
    const int tid = threadIdx.x;
    const int n0 = blockIdx.x * 64;
    const int ty = tid >> 5, tx = tid & 31;   // rows 8*ty..8*ty+7, cols 4*tx..4*tx+3

    float acc[8][4];
#pragma unroll
    for (int i = 0; i < 8; ++i)
#pragma unroll
        for (int j = 0; j < 4; ++j) acc[i][j] = 0.f;

    for (int k0 = 0; k0 < 256; k0 += 16) {
        // stage x tile (64 rows x 16 k), transposed into xs[k][row]
        {
            int row = tid >> 2, q = tid & 3;
            int gr = n0 + row;
            float4 v = make_float4(0.f, 0.f, 0.f, 0.f);
            if (gr < n) v = *(const float4*)(x + (size_t)gr * 256 + k0 + 4 * q);
            xs[4 * q + 0][row] = v.x;
            xs[4 * q + 1][row] = v.y;
            xs[4 * q + 2][row] = v.z;
            xs[4 * q + 3][row] = v.w;
        }
        // stage W1 tile (16 k x 128 cols)
#pragma unroll
        for (int r2 = 0; r2 < 2; ++r2) {
            int ii = r2 * 256 + tid;
            int kr = ii >> 5, cq = ii & 31;
            float4 v = *(const float4*)(w1 + (size_t)(k0 + kr) * 128 + 4 * cq);
            *(float4*)&ws[kr][4 * cq] = v;
        }
        __syncthreads();
#pragma unroll
        for (int k = 0; k < 16; ++k) {
            float4 xa = *(const float4*)&xs[k][8 * ty];
            float4 xb = *(const float4*)&xs[k][8 * ty + 4];
            float4 wv = *(const float4*)&ws[k][4 * tx];
            float xr[8] = {xa.x, xa.y, xa.z, xa.w, xb.x, xb.y, xb.z, xb.w};
            float wr[4] = {wv.x, wv.y, wv.z, wv.w};
#pragma unroll
            for (int i = 0; i < 8; ++i)
#pragma unroll
                for (int j = 0; j < 4; ++j) acc[i][j] = fmaf(xr[i], wr[j], acc[i][j]);
        }
        __syncthreads();
    }
    // epilogue: convert to bf16, coalesced ushort4 stores
#pragma unroll
    for (int i = 0; i < 8; ++i) {
        int gr = n0 + 8 * ty + i;
        if (gr < n) {
            ushort4 o;
            o.x = f2bf(acc[i][0]);
            o.y = f2bf(acc[i][1]);
            o.z = f2bf(acc[i][2]);
            o.w = f2bf(acc[i][3]);
            *(ushort4*)(hbf + (size_t)gr * 128 + 4 * tx) = o;
        }
    }
}

// ---------------- Agg1: h1 = relu(segsum(h[src]*w) + b1), f32 out ----------------
__global__ __launch_bounds__(256) void k_agg1(const u16* __restrict__ hbf,
                                              const int* __restrict__ off,
                                              const int* __restrict__ csrs,
                                              const float* __restrict__ csrw,
                                              const float* __restrict__ b1,
                                              float* __restrict__ h1, int n) {
    const int t = threadIdx.x;
    const int node = blockIdx.x * 8 + (t >> 5);
    if (node >= n) return;
    const int fq = (t & 31) * 4;
    const int e0 = off[node], e1 = off[node + 1];
    float a0 = 0.f, a1 = 0.f, a2 = 0.f, a3 = 0.f;
    int e = e0;
    for (; e + 1 < e1; e += 2) {
        int s0 = csrs[e];
        float w0 = csrw[e];
        int s1 = csrs[e + 1];
        float w1 = csrw[e + 1];
        ushort4 v0 = *(const ushort4*)(hbf + (size_t)s0 * 128 + fq);
        ushort4 v1 = *(const ushort4*)(hbf + (size_t)s1 * 128 + fq);
        a0 = fmaf(bf2f(v0.x), w0, a0);
        a1 = fmaf(bf2f(v0.y), w0, a1);
        a2 = fmaf(bf2f(v0.z), w0, a2);
        a3 = fmaf(bf2f(v0.w), w0, a3);
        a0 = fmaf(bf2f(v1.x), w1, a0);
        a1 = fmaf(bf2f(v1.y), w1, a1);
        a2 = fmaf(bf2f(v1.z), w1, a2);
        a3 = fmaf(bf2f(v1.w), w1, a3);
    }
    if (e < e1) {
        int s0 = csrs[e];
        float w0 = csrw[e];
        ushort4 v0 = *(const ushort4*)(hbf + (size_t)s0 * 128 + fq);
        a0 = fmaf(bf2f(v0.x), w0, a0);
        a1 = fmaf(bf2f(v0.y), w0, a1);
        a2 = fmaf(bf2f(v0.z), w0, a2);
        a3 = fmaf(bf2f(v0.w), w0, a3);
    }
    float4 bb = *(const float4*)(b1 + fq);
    float4 r;
    r.x = fmaxf(a0 + bb.x, 0.f);
    r.y = fmaxf(a1 + bb.y, 0.f);
    r.z = fmaxf(a2 + bb.z, 0.f);
    r.w = fmaxf(a3 + bb.w, 0.f);
    *(float4*)(h1 + (size_t)node * 128 + fq) = r;
}

// ---------------- GEMM2: h2 = h1 @ W2 ([N,128]@[128,40]) -> bf16 ----------------
__global__ __launch_bounds__(64) void k_gemm2(const float* __restrict__ h1,
                                              const float* __restrict__ w2,
                                              u16* __restrict__ h2, int n) {
    __shared__ float hs[64 * 132];   // [node][k], pad 132 (33 quads, stride 1 mod 8)
    const int t = threadIdx.x;
    const int n0 = blockIdx.x * 64;
    const float* src = h1 + (size_t)n0 * 128;
#pragma unroll
    for (int i = 0; i < 32; ++i) {
        int idx = i * 64 + t;
        int r = idx >> 5, q = idx & 31;
        float4 v = make_float4(0.f, 0.f, 0.f, 0.f);
        if (n0 + r < n) v = *(const float4*)(src + (size_t)r * 128 + 4 * q);
        *(float4*)&hs[r * 132 + 4 * q] = v;
    }
    __syncthreads();

    float acc[40];
#pragma unroll
    for (int c = 0; c < 40; ++c) acc[c] = 0.f;

    for (int k4 = 0; k4 < 32; ++k4) {
        float4 hv = *(const float4*)&hs[t * 132 + 4 * k4];
#pragma unroll
        for (int j = 0; j < 4; ++j) {
            float xv = (j == 0) ? hv.x : (j == 1) ? hv.y : (j == 2) ? hv.z : hv.w;
            const float* wr = w2 + (size_t)(4 * k4 + j) * 40;   // wave-uniform -> s_load
#pragma unroll
            for (int c = 0; c < 40; ++c) acc[c] = fmaf(xv, wr[c], acc[c]);
        }
    }
    __syncthreads();
    // stage bf16 output in LDS then coalesced copy-out
    u16* hsu = (u16*)&hs[0];
#pragma unroll
    for (int c = 0; c < 40; ++c) hsu[t * 40 + c] = f2bf(acc[c]);
    __syncthreads();
    const int lim = (n - n0 < 64 ? n - n0 : 64) * 40;   // u16 count valid in this block
    u16* dst = h2 + (size_t)n0 * 40;
#pragma unroll
    for (int i = 0; i < 10; ++i) {
        int idx4 = i * 64 + t;
        if (idx4 * 4 < lim) {
            ushort4 v = ((const ushort4*)hsu)[idx4];
            *(ushort4*)(dst + idx4 * 4) = v;
        }
    }
}

// ---------------- Agg2 + bias + log_softmax fused ----------------
__global__ __launch_bounds__(256) void k_agg2(const u16* __restrict__ h2,
                                              const int* __restrict__ off,
                                              const int* __restrict__ csrs,
                                              const float* __restrict__ csrw,
                                              const float* __restrict__ b2,
                                              float* __restrict__ out, int n) {
    const int t = threadIdx.x;
    const int node = blockIdx.x * 4 + (t >> 6);
    if (node >= n) return;     // wave-uniform exit
    const int f = t & 63;
    float acc = 0.f;
    const int e0 = off[node], e1 = off[node + 1];
    if (f < 40) {
        int e = e0;
        for (; e + 1 < e1; e += 2) {
            int s0 = csrs[e];
            float w0 = csrw[e];
            int s1 = csrs[e + 1];
            float w1 = csrw[e + 1];
            acc = fmaf(bf2f(h2[(size_t)s0 * 40 + f]), w0, acc);
            acc = fmaf(bf2f(h2[(size_t)s1 * 40 + f]), w1, acc);
        }
        if (e < e1) {
            int s0 = csrs[e];
            acc = fmaf(bf2f(h2[(size_t)s0 * 40 + f]), csrw[e], acc);
        }
    }
    float v = (f < 40) ? acc + b2[f] : -INFINITY;
    float m = v;
#pragma unroll
    for (int d = 32; d > 0; d >>= 1) m = fmaxf(m, __shfl_xor(m, d, 64));
    float ev = (f < 40) ? __expf(v - m) : 0.f;
    float s = ev;
#pragma unroll
    for (int d = 32; d > 0; d >>= 1) s += __shfl_xor(s, d, 64);
    if (f < 40) out[(size_t)node * 40 + f] = v - m - logf(s);
}

extern "C" void kernel_launch(void* const* d_in, const int* in_sizes, int n_in,
                              void* d_out, int out_size, void* d_ws, size_t ws_size,
                              hipStream_t stream) {
    const float* x = (const float*)d_in[0];
    const int* ei = (const int*)d_in[1];        // harness delivers integers as int32
    const float* w1 = (const float*)d_in[2];
    const float* b1 = (const float*)d_in[3];
    const float* w2 = (const float*)d_in[4];
    const float* b2 = (const float*)d_in[5];
    float* out = (float*)d_out;

    const int N = in_sizes[0] / 256;
    const int E = in_sizes[1] / 2;
    const int T = E + N;

    char* p = (char*)d_ws;
    auto alloc = [&](size_t bytes) {
        char* r = p;
        p += (bytes + 255) & ~(size_t)255;
        return r;
    };
    int* deg = (int*)alloc((size_t)N * 4);
    float* dinv = (float*)alloc((size_t)N * 4);
    int* off = (int*)alloc((size_t)(N + 1) * 4);
    int* cursor = (int*)alloc((size_t)N * 4);
    int* part = (int*)alloc(4096);
    int* csrs = (int*)alloc((size_t)T * 4);
    float* csrw = (float*)alloc((size_t)T * 4);
    u16* hbf = (u16*)alloc((size_t)N * 128 * 2);
    float* h1 = (float*)alloc((size_t)N * 128 * 4);
    u16* h2 = hbf;   // reuse: hbf dead after agg1

    const int nb = (N + 1023) / 1024;

    k_init_deg<<<(N + 255) / 256, 256, 0, stream>>>(deg, N);
    k_hist<<<(E + 255) / 256, 256, 0, stream>>>(ei + E, deg, E, N);
    k_dinv<<<(N + 255) / 256, 256, 0, stream>>>(deg, dinv, N);
    k_scan1<<<nb, 1024, 0, stream>>>(deg, off, part, N);
    k_scan2<<<1, 1024, 0, stream>>>(part, nb);
    k_scan3<<<(N + 1 + 255) / 256, 256, 0, stream>>>(off, cursor, part, N);
    k_fill<<<(T + 255) / 256, 256, 0, stream>>>(ei, dinv, cursor, csrs, csrw, E, N);
    k_gemm1<<<(N + 63) / 64, 256, 0, stream>>>(x, w1, hbf, N);
    k_agg1<<<(N + 7) / 8, 256, 0, stream>>>(hbf, off, csrs, csrw, b1, h1, N);
    k_gemm2<<<(N + 63) / 64, 64, 0, stream>>>(h1, w2, h2, N);
    k_agg2<<<(N + 3) / 4, 256, 0, stream>>>(h2, off, csrs, csrw, b2, out, N);
}

// Round 3
// 491.592 us; speedup vs baseline: 1.0842x; 1.0842x over previous
//
#include <hip/hip_runtime.h>
#include <hip/hip_bf16.h>
#include <math.h>
#include <stdint.h>

typedef unsigned short u16;
typedef __attribute__((ext_vector_type(8))) short short8;
typedef __attribute__((ext_vector_type(4))) float f32x4;

__device__ __forceinline__ u16 bfbits(float f) {
    __hip_bfloat16 h = __float2bfloat16(f);   // RNE; compiler fuses pairs to v_cvt_pk_bf16_f32
    return *reinterpret_cast<u16*>(&h);
}
__device__ __forceinline__ float bf2f(u16 b) {
    return __uint_as_float((uint32_t)b << 16);
}

// ---------------- degree / norm ----------------
__global__ void k_init_deg(int* __restrict__ deg, int n) {
    int i = blockIdx.x * blockDim.x + threadIdx.x;
    if (i < n) deg[i] = 1;                    // self-loop
}

__global__ void k_hist(const int* __restrict__ col, int* __restrict__ deg, int E, int n) {
    int e = blockIdx.x * blockDim.x + threadIdx.x;
    if (e < E) {
        int c = col[e];
        if ((unsigned)c < (unsigned)n) atomicAdd(&deg[c], 1);
    }
}

__global__ void k_dinv(const int* __restrict__ deg, float* __restrict__ dinv, int n) {
    int i = blockIdx.x * blockDim.x + threadIdx.x;
    if (i < n) dinv[i] = rsqrtf((float)deg[i]);   // deg >= 1 always (self-loop)
}

// ---------------- exclusive scan (3 kernels) ----------------
__global__ void k_scan1(const int* __restrict__ cnt, int* __restrict__ excl,
                        int* __restrict__ part, int n) {
    __shared__ int sh[1024];
    int i = blockIdx.x * 1024 + threadIdx.x;
    int v = (i < n) ? cnt[i] : 0;
    sh[threadIdx.x] = v;
    __syncthreads();
    for (int d = 1; d < 1024; d <<= 1) {
        int t = (threadIdx.x >= (unsigned)d) ? sh[threadIdx.x - d] : 0;
        __syncthreads();
        sh[threadIdx.x] += t;
        __syncthreads();
    }
    if (i < n) excl[i] = sh[threadIdx.x] - v;
    if (threadIdx.x == 1023) part[blockIdx.x] = sh[1023];
}

__global__ void k_scan2(int* __restrict__ part, int nb) {
    __shared__ int sh[1024];
    int v = ((int)threadIdx.x < nb) ? part[threadIdx.x] : 0;
    sh[threadIdx.x] = v;
    __syncthreads();
    for (int d = 1; d < 1024; d <<= 1) {
        int t = (threadIdx.x >= (unsigned)d) ? sh[threadIdx.x - d] : 0;
        __syncthreads();
        sh[threadIdx.x] += t;
        __syncthreads();
    }
    if ((int)threadIdx.x < nb) part[threadIdx.x] = sh[threadIdx.x] - v;  // exclusive
    if (threadIdx.x == 0) part[nb] = sh[1023];                            // total
}

__global__ void k_scan3(int* __restrict__ off, int* __restrict__ cursor,
                        const int* __restrict__ part, int n) {
    int i = blockIdx.x * blockDim.x + threadIdx.x;
    if (i < n) {
        int o = off[i] + part[i >> 10];
        off[i] = o;
        cursor[i] = o;
    } else if (i == n) {
        off[n] = part[(n + 1023) >> 10];
    }
}

// ---------------- CSR fill: sources only (weights recomputed from dinv) ----------------
__global__ void k_fill(const int* __restrict__ ei, int* __restrict__ cursor,
                       int* __restrict__ csrs, int E, int n) {
    int i = blockIdx.x * blockDim.x + threadIdx.x;
    if (i < E) {
        int r = ei[i], c = ei[E + i];
        if ((unsigned)r < (unsigned)n && (unsigned)c < (unsigned)n) {
            int p = atomicAdd(&cursor[c], 1);
            csrs[p] = r;
        }
    } else if (i < E + n) {
        int c = i - E;
        int p = atomicAdd(&cursor[c], 1);
        csrs[p] = c;          // self-loop: src == dst, weight dinv^2 falls out naturally
    }
}

// ---------------- W1 -> bf16, pre-swizzled into B-fragment order ----------------
// frag f = ct*8 + kt (ct: 16-col tile, kt: 32-k tile); lane l elem e:
//   W1[kt*32 + (l>>4)*8 + e][ct*16 + (l&15)]  stored at  w1bf[(f*64 + l)*8 + e]
__global__ void k_w1bf(const float* __restrict__ w1, short* __restrict__ w1bf) {
    int i = blockIdx.x * 256 + threadIdx.x;    // 32768 total
    int e = i & 7, l = (i >> 3) & 63, kt = (i >> 9) & 7, ct = i >> 12;
    int k = kt * 32 + (l >> 4) * 8 + e;
    int c = ct * 16 + (l & 15);
    w1bf[i] = (short)bfbits(w1[(size_t)k * 128 + c]);
}

// ---------------- GEMM1 (MFMA bf16): h = x @ W1  ([N,256]@[256,128]) -> bf16 ----------------
// Block: 64 nodes x 128 cols, 4 waves in 2x2 grid (wave: 32 nodes x 64 cols).
// Per wave: 2 M-frags x 4 N-frags, K-loop of 8 x (K=32). No LDS, no barriers.
__global__ __launch_bounds__(256) void k_gemm1(const float* __restrict__ x,
                                               const short* __restrict__ w1bf,
                                               u16* __restrict__ hbf, int n) {
    const int tid = threadIdx.x;
    const int wv = tid >> 6, l = tid & 63;
    const int mrow = wv >> 1, mcol = wv & 1;
    const int lr = l & 15, kg = l >> 4;       // lr: row/col within frag; kg: k-group
    const int n0 = blockIdx.x * 64;

    f32x4 zero = {0.f, 0.f, 0.f, 0.f};
    f32x4 acc[2][4];
#pragma unroll
    for (int m = 0; m < 2; ++m)
#pragma unroll
        for (int c = 0; c < 4; ++c) acc[m][c] = zero;

    // A source pointers (row-clamped for the tail block)
    const float* xp[2];
#pragma unroll
    for (int m = 0; m < 2; ++m) {
        int row = n0 + 32 * mrow + 16 * m + lr;
        if (row > n - 1) row = n - 1;
        xp[m] = x + (size_t)row * 256 + kg * 8;
    }
    const short* bbase = w1bf + ((size_t)(4 * mcol) * 8) * 64 * 8 + (size_t)l * 8;

#pragma unroll 2
    for (int kt = 0; kt < 8; ++kt) {
        short8 afrag[2];
#pragma unroll
        for (int m = 0; m < 2; ++m) {
            float4 u = *(const float4*)(xp[m] + kt * 32);
            float4 v = *(const float4*)(xp[m] + kt * 32 + 4);
            short8 a;
            a[0] = (short)bfbits(u.x);
            a[1] = (short)bfbits(u.y);
            a[2] = (short)bfbits(u.z);
            a[3] = (short)bfbits(u.w);
            a[4] = (short)bfbits(v.x);
            a[5] = (short)bfbits(v.y);
            a[6] = (short)bfbits(v.z);
            a[7] = (short)bfbits(v.w);
            afrag[m] = a;
        }
#pragma unroll
        for (int c = 0; c < 4; ++c) {
            short8 bfrag = *(const short8*)(bbase + ((size_t)(c * 8 + kt) * 64) * 8);
#pragma unroll
            for (int m = 0; m < 2; ++m)
                acc[m][c] = __builtin_amdgcn_mfma_f32_16x16x32_bf16(afrag[m], bfrag,
                                                                    acc[m][c], 0, 0, 0);
        }
    }

    // epilogue: D mapping col=lane&15, row=(lane>>4)*4+r  [m89-verified]
#pragma unroll
    for (int m = 0; m < 2; ++m) {
        int rbase = n0 + 32 * mrow + 16 * m + kg * 4;
#pragma unroll
        for (int r = 0; r < 4; ++r) {
            int row = rbase + r;
            if (row < n) {
#pragma unroll
                for (int c = 0; c < 4; ++c) {
                    int col = 64 * mcol + 16 * c + lr;
                    hbf[(size_t)row * 128 + col] = bfbits(acc[m][c][r]);
                }
            }
        }
    }
}

// ---------------- Agg1: h1 = relu(segsum(h[src]*dinv[src])*dinv[node] + b1) ----------------
__global__ __launch_bounds__(256) void k_agg1(const u16* __restrict__ hbf,
                                              const int* __restrict__ off,
                                              const int* __restrict__ csrs,
                                              const float* __restrict__ dinv,
                                              const float* __restrict__ b1,
                                              float* __restrict__ h1, int n) {
    const int t = threadIdx.x;
    const int node = blockIdx.x * 8 + (t >> 5);
    if (node >= n) return;
    const int fq = (t & 31) * 4;
    const float dn = dinv[node];
    const int e0 = off[node], e1 = off[node + 1];
    float a0 = 0.f, a1 = 0.f, a2 = 0.f, a3 = 0.f;
    int e = e0;
    for (; e + 1 < e1; e += 2) {
        int s0 = csrs[e];
        int s1 = csrs[e + 1];
        float w0 = dinv[s0] * dn;
        float w1 = dinv[s1] * dn;
        ushort4 v0 = *(const ushort4*)(hbf + (size_t)s0 * 128 + fq);
        ushort4 v1 = *(const ushort4*)(hbf + (size_t)s1 * 128 + fq);
        a0 = fmaf(bf2f(v0.x), w0, a0);
        a1 = fmaf(bf2f(v0.y), w0, a1);
        a2 = fmaf(bf2f(v0.z), w0, a2);
        a3 = fmaf(bf2f(v0.w), w0, a3);
        a0 = fmaf(bf2f(v1.x), w1, a0);
        a1 = fmaf(bf2f(v1.y), w1, a1);
        a2 = fmaf(bf2f(v1.z), w1, a2);
        a3 = fmaf(bf2f(v1.w), w1, a3);
    }
    if (e < e1) {
        int s0 = csrs[e];
        float w0 = dinv[s0] * dn;
        ushort4 v0 = *(const ushort4*)(hbf + (size_t)s0 * 128 + fq);
        a0 = fmaf(bf2f(v0.x), w0, a0);
        a1 = fmaf(bf2f(v0.y), w0, a1);
        a2 = fmaf(bf2f(v0.z), w0, a2);
        a3 = fmaf(bf2f(v0.w), w0, a3);
    }
    float4 bb = *(const float4*)(b1 + fq);
    float4 r;
    r.x = fmaxf(a0 + bb.x, 0.f);
    r.y = fmaxf(a1 + bb.y, 0.f);
    r.z = fmaxf(a2 + bb.z, 0.f);
    r.w = fmaxf(a3 + bb.w, 0.f);
    *(float4*)(h1 + (size_t)node * 128 + fq) = r;
}

// ---------------- GEMM2: h2 = h1 @ W2 ([N,128]@[128,40]) -> bf16 ----------------
__global__ __launch_bounds__(64) void k_gemm2(const float* __restrict__ h1,
                                              const float* __restrict__ w2,
                                              u16* __restrict__ h2, int n) {
    __shared__ float hs[64 * 132];   // [node][k], pad 132
    const int t = threadIdx.x;
    const int n0 = blockIdx.x * 64;
    const float* src = h1 + (size_t)n0 * 128;
#pragma unroll
    for (int i = 0; i < 32; ++i) {
        int idx = i * 64 + t;
        int r = idx >> 5, q = idx & 31;
        float4 v = make_float4(0.f, 0.f, 0.f, 0.f);
        if (n0 + r < n) v = *(const float4*)(src + (size_t)r * 128 + 4 * q);
        *(float4*)&hs[r * 132 + 4 * q] = v;
    }
    __syncthreads();

    float acc[40];
#pragma unroll
    for (int c = 0; c < 40; ++c) acc[c] = 0.f;

    for (int k4 = 0; k4 < 32; ++k4) {
        float4 hv = *(const float4*)&hs[t * 132 + 4 * k4];
#pragma unroll
        for (int j = 0; j < 4; ++j) {
            float xv = (j == 0) ? hv.x : (j == 1) ? hv.y : (j == 2) ? hv.z : hv.w;
            const float* wr = w2 + (size_t)(4 * k4 + j) * 40;   // wave-uniform -> s_load
#pragma unroll
            for (int c = 0; c < 40; ++c) acc[c] = fmaf(xv, wr[c], acc[c]);
        }
    }
    __syncthreads();
    u16* hsu = (u16*)&hs[0];
#pragma unroll
    for (int c = 0; c < 40; ++c) hsu[t * 40 + c] = bfbits(acc[c]);
    __syncthreads();
    const int lim = (n - n0 < 64 ? n - n0 : 64) * 40;
    u16* dst = h2 + (size_t)n0 * 40;
#pragma unroll
    for (int i = 0; i < 10; ++i) {
        int idx4 = i * 64 + t;
        if (idx4 * 4 < lim) {
            ushort4 v = ((const ushort4*)hsu)[idx4];
            *(ushort4*)(dst + idx4 * 4) = v;
        }
    }
}

// ---------------- Agg2 + bias + log_softmax fused ----------------
__global__ __launch_bounds__(256) void k_agg2(const u16* __restrict__ h2,
                                              const int* __restrict__ off,
                                              const int* __restrict__ csrs,
                                              const float* __restrict__ dinv,
                                              const float* __restrict__ b2,
                                              float* __restrict__ out, int n) {
    const int t = threadIdx.x;
    const int node = blockIdx.x * 4 + (t >> 6);
    if (node >= n) return;     // wave-uniform exit
    const int f = t & 63;
    const float dn = dinv[node];
    float acc = 0.f;
    const int e0 = off[node], e1 = off[node + 1];
    if (f < 40) {
        int e = e0;
        for (; e + 1 < e1; e += 2) {
            int s0 = csrs[e];
            int s1 = csrs[e + 1];
            float w0 = dinv[s0] * dn;
            float w1 = dinv[s1] * dn;
            acc = fmaf(bf2f(h2[(size_t)s0 * 40 + f]), w0, acc);
            acc = fmaf(bf2f(h2[(size_t)s1 * 40 + f]), w1, acc);
        }
        if (e < e1) {
            int s0 = csrs[e];
            acc = fmaf(bf2f(h2[(size_t)s0 * 40 + f]), dinv[s0] * dn, acc);
        }
    }
    float v = (f < 40) ? acc + b2[f] : -INFINITY;
    float m = v;
#pragma unroll
    for (int d = 32; d > 0; d >>= 1) m = fmaxf(m, __shfl_xor(m, d, 64));
    float ev = (f < 40) ? __expf(v - m) : 0.f;
    float s = ev;
#pragma unroll
    for (int d = 32; d > 0; d >>= 1) s += __shfl_xor(s, d, 64);
    if (f < 40) out[(size_t)node * 40 + f] = v - m - logf(s);
}

extern "C" void kernel_launch(void* const* d_in, const int* in_sizes, int n_in,
                              void* d_out, int out_size, void* d_ws, size_t ws_size,
                              hipStream_t stream) {
    const float* x = (const float*)d_in[0];
    const int* ei = (const int*)d_in[1];        // harness delivers integers as int32
    const float* w1 = (const float*)d_in[2];
    const float* b1 = (const float*)d_in[3];
    const float* w2 = (const float*)d_in[4];
    const float* b2 = (const float*)d_in[5];
    float* out = (float*)d_out;

    const int N = in_sizes[0] / 256;
    const int E = in_sizes[1] / 2;
    const int T = E + N;

    char* p = (char*)d_ws;
    auto alloc = [&](size_t bytes) {
        char* r = p;
        p += (bytes + 255) & ~(size_t)255;
        return r;
    };
    int* deg = (int*)alloc((size_t)N * 4);
    float* dinv = (float*)alloc((size_t)N * 4);
    int* off = (int*)alloc((size_t)(N + 1) * 4);
    int* cursor = (int*)alloc((size_t)N * 4);
    int* part = (int*)alloc(4096);
    int* csrs = (int*)alloc((size_t)T * 4);
    short* w1bf = (short*)alloc(32768 * 2);
    u16* hbf = (u16*)alloc((size_t)N * 128 * 2);
    float* h1 = (float*)alloc((size_t)N * 128 * 4);
    u16* h2 = hbf;   // reuse: hbf dead after agg1

    const int nb = (N + 1023) / 1024;

    k_init_deg<<<(N + 255) / 256, 256, 0, stream>>>(deg, N);
    k_hist<<<(E + 255) / 256, 256, 0, stream>>>(ei + E, deg, E, N);
    k_dinv<<<(N + 255) / 256, 256, 0, stream>>>(deg, dinv, N);
    k_scan1<<<nb, 1024, 0, stream>>>(deg, off, part, N);
    k_scan2<<<1, 1024, 0, stream>>>(part, nb);
    k_scan3<<<(N + 1 + 255) / 256, 256, 0, stream>>>(off, cursor, part, N);
    k_fill<<<(T + 255) / 256, 256, 0, stream>>>(ei, cursor, csrs, E, N);
    k_w1bf<<<128, 256, 0, stream>>>(w1, w1bf);
    k_gemm1<<<(N + 63) / 64, 256, 0, stream>>>(x, w1bf, hbf, N);
    k_agg1<<<(N + 7) / 8, 256, 0, stream>>>(hbf, off, csrs, dinv, b1, h1, N);
    k_gemm2<<<(N + 63) / 64, 64, 0, stream>>>(h1, w2, h2, N);
    k_agg2<<<(N + 3) / 4, 256, 0, stream>>>(h2, off, csrs, dinv, b2, out, N);
}

// Round 4
// 350.069 us; speedup vs baseline: 1.5225x; 1.4043x over previous
//
#include <hip/hip_runtime.h>
#include <hip/hip_bf16.h>
#include <math.h>
#include <stdint.h>

typedef unsigned short u16;
typedef unsigned int u32;
typedef __attribute__((ext_vector_type(8))) short short8;
typedef __attribute__((ext_vector_type(4))) float f32x4;

#define BN 256      // nodes per bucket (power of 2)
#define NBMAX 400   // max buckets (N<=102400)
#define EPB 4096    // edges per block in count/scatter

__device__ __forceinline__ u16 bfbits(float f) {
    __hip_bfloat16 h = __float2bfloat16(f);   // RNE; pairs fuse to v_cvt_pk_bf16_f32
    return *reinterpret_cast<u16*>(&h);
}
__device__ __forceinline__ float bf2f(u16 b) {
    return __uint_as_float((uint32_t)b << 16);
}

// ---------------- bucket counts (block-aggregated) ----------------
__global__ __launch_bounds__(256) void k_cnt(const int* __restrict__ col,
                                             int* __restrict__ gcnt, int E, int n, int nb) {
    __shared__ int sh[NBMAX];
    const int t = threadIdx.x;
    for (int i = t; i < nb; i += 256) sh[i] = 0;
    __syncthreads();
    const int base = blockIdx.x * EPB;
#pragma unroll
    for (int j = 0; j < 16; ++j) {
        int e = base + j * 256 + t;
        if (e < E) {
            unsigned c = (unsigned)col[e];
            if (c < (unsigned)n) atomicAdd(&sh[c >> 8], 1);
        }
    }
    __syncthreads();
    for (int i = t; i < nb; i += 256)
        if (sh[i]) atomicAdd(&gcnt[i], sh[i]);
}

// ---------------- bucket scan (single block) ----------------
__global__ __launch_bounds__(512) void k_bscan(const int* __restrict__ gcnt,
                                               int* __restrict__ ebase, int* __restrict__ cursor,
                                               int* __restrict__ off, int nb, int n) {
    __shared__ int sh[512];
    const int t = threadIdx.x;
    int v = (t < nb) ? gcnt[t] : 0;
    sh[t] = v;
    __syncthreads();
    for (int d = 1; d < 512; d <<= 1) {
        int x = (t >= d) ? sh[t - d] : 0;
        __syncthreads();
        sh[t] += x;
        __syncthreads();
    }
    if (t < nb) {
        int excl = sh[t] - v;
        ebase[t] = excl;
        cursor[t] = excl;
    }
    if (t == 0) {
        ebase[nb] = sh[511];        // total (valid) edges
        off[n] = sh[511] + n;       // csr total incl. self-loops
    }
}

// ---------------- scatter edges to bucket-contiguous staging ----------------
// staging word: src (17 bits) | c_local (8 bits) << 17
__global__ __launch_bounds__(256) void k_scat(const int* __restrict__ ei,
                                              int* __restrict__ cursor,
                                              u32* __restrict__ staging, int E, int n, int nb) {
    __shared__ int cnt[NBMAX];
    __shared__ int cbase[NBMAX];
    const int t = threadIdx.x;
    for (int i = t; i < nb; i += 256) cnt[i] = 0;
    __syncthreads();
    const int base = blockIdx.x * EPB;
    int rr[16], cc[16], rk[16];
#pragma unroll
    for (int j = 0; j < 16; ++j) {
        int e = base + j * 256 + t;
        cc[j] = -1;
        if (e < E) {
            unsigned r = (unsigned)ei[e], c = (unsigned)ei[E + e];
            if (r < (unsigned)n && c < (unsigned)n) {
                rr[j] = (int)r;
                cc[j] = (int)c;
                rk[j] = atomicAdd(&cnt[c >> 8], 1);
            }
        }
    }
    __syncthreads();
    for (int i = t; i < nb; i += 256)
        if (cnt[i]) cbase[i] = atomicAdd(&cursor[i], cnt[i]);
    __syncthreads();
#pragma unroll
    for (int j = 0; j < 16; ++j) {
        if (cc[j] >= 0) {
            int b = cc[j] >> 8;
            staging[cbase[b] + rk[j]] = (u32)rr[j] | ((u32)(cc[j] & (BN - 1)) << 17);
        }
    }
}

// ---------------- per-bucket CSR build: deg, dinv, off, csrs ----------------
__global__ __launch_bounds__(256) void k_build(const u32* __restrict__ staging,
                                               const int* __restrict__ ebase,
                                               int* __restrict__ csrs, int* __restrict__ off,
                                               float* __restrict__ dinv, int n) {
    __shared__ int sh[256];
    __shared__ int cur[256];
    const int t = threadIdx.x;
    const int b = blockIdx.x;
    const int e0 = ebase[b], e1 = ebase[b + 1];
    const int node0 = b * BN;
    const int nn = min(BN, n - node0);
    sh[t] = 0;
    __syncthreads();
    for (int i = e0 + t; i < e1; i += 256)
        atomicAdd(&sh[staging[i] >> 17], 1);
    __syncthreads();
    const int mycnt = sh[t];
    const int myval = (t < nn) ? mycnt + 1 : 0;   // +1 self-loop
    sh[t] = myval;                                // own-slot read->write, no race
    __syncthreads();
    for (int d = 1; d < 256; d <<= 1) {
        int x = (t >= d) ? sh[t - d] : 0;
        __syncthreads();
        sh[t] += x;
        __syncthreads();
    }
    const int excl = sh[t] - myval;
    const int csrbase = e0 + node0;               // edges-before + selfloops-before
    if (t < nn) {
        int node = node0 + t;
        int o = csrbase + excl;
        off[node] = o;
        dinv[node] = rsqrtf((float)(mycnt + 1));
        csrs[o] = node;                           // self-loop first in segment
        cur[t] = o + 1;
    }
    __syncthreads();
    for (int i = e0 + t; i < e1; i += 256) {
        u32 v = staging[i];
        int p = atomicAdd(&cur[v >> 17], 1);
        csrs[p] = (int)(v & 0x1FFFF);
    }
}

// ---------------- W1 -> bf16, pre-swizzled into B-fragment order ----------------
__global__ void k_w1bf(const float* __restrict__ w1, short* __restrict__ w1bf) {
    int i = blockIdx.x * 256 + threadIdx.x;    // 32768 total
    int e = i & 7, l = (i >> 3) & 63, kt = (i >> 9) & 7, ct = i >> 12;
    int k = kt * 32 + (l >> 4) * 8 + e;
    int c = ct * 16 + (l & 15);
    w1bf[i] = (short)bfbits(w1[(size_t)k * 128 + c]);
}

// ---------------- GEMM1 (MFMA bf16): h = x @ W1 -> bf16 ----------------
__global__ __launch_bounds__(256) void k_gemm1(const float* __restrict__ x,
                                               const short* __restrict__ w1bf,
                                               u16* __restrict__ hbf, int n) {
    const int tid = threadIdx.x;
    const int wv = tid >> 6, l = tid & 63;
    const int mrow = wv >> 1, mcol = wv & 1;
    const int lr = l & 15, kg = l >> 4;
    const int n0 = blockIdx.x * 64;

    f32x4 zero = {0.f, 0.f, 0.f, 0.f};
    f32x4 acc[2][4];
#pragma unroll
    for (int m = 0; m < 2; ++m)
#pragma unroll
        for (int c = 0; c < 4; ++c) acc[m][c] = zero;

    const float* xp[2];
#pragma unroll
    for (int m = 0; m < 2; ++m) {
        int row = n0 + 32 * mrow + 16 * m + lr;
        if (row > n - 1) row = n - 1;
        xp[m] = x + (size_t)row * 256 + kg * 8;
    }
    const short* bbase = w1bf + ((size_t)(4 * mcol) * 8) * 64 * 8 + (size_t)l * 8;

#pragma unroll 2
    for (int kt = 0; kt < 8; ++kt) {
        short8 afrag[2];
#pragma unroll
        for (int m = 0; m < 2; ++m) {
            float4 u = *(const float4*)(xp[m] + kt * 32);
            float4 v = *(const float4*)(xp[m] + kt * 32 + 4);
            short8 a;
            a[0] = (short)bfbits(u.x);
            a[1] = (short)bfbits(u.y);
            a[2] = (short)bfbits(u.z);
            a[3] = (short)bfbits(u.w);
            a[4] = (short)bfbits(v.x);
            a[5] = (short)bfbits(v.y);
            a[6] = (short)bfbits(v.z);
            a[7] = (short)bfbits(v.w);
            afrag[m] = a;
        }
#pragma unroll
        for (int c = 0; c < 4; ++c) {
            short8 bfrag = *(const short8*)(bbase + ((size_t)(c * 8 + kt) * 64) * 8);
#pragma unroll
            for (int m = 0; m < 2; ++m)
                acc[m][c] = __builtin_amdgcn_mfma_f32_16x16x32_bf16(afrag[m], bfrag,
                                                                    acc[m][c], 0, 0, 0);
        }
    }

#pragma unroll
    for (int m = 0; m < 2; ++m) {
        int rbase = n0 + 32 * mrow + 16 * m + kg * 4;
#pragma unroll
        for (int r = 0; r < 4; ++r) {
            int row = rbase + r;
            if (row < n) {
#pragma unroll
                for (int c = 0; c < 4; ++c) {
                    int col = 64 * mcol + 16 * c + lr;
                    hbf[(size_t)row * 128 + col] = bfbits(acc[m][c][r]);
                }
            }
        }
    }
}

// ---------------- Agg1: h1 = relu(segsum(h[src]*dinv[src])*dinv[node] + b1) ----------------
__global__ __launch_bounds__(256) void k_agg1(const u16* __restrict__ hbf,
                                              const int* __restrict__ off,
                                              const int* __restrict__ csrs,
                                              const float* __restrict__ dinv,
                                              const float* __restrict__ b1,
                                              float* __restrict__ h1, int n) {
    const int t = threadIdx.x;
    const int node = blockIdx.x * 8 + (t >> 5);
    if (node >= n) return;
    const int fq = (t & 31) * 4;
    const float dn = dinv[node];
    const int e0 = off[node], e1 = off[node + 1];
    float a0 = 0.f, a1 = 0.f, a2 = 0.f, a3 = 0.f;
    int e = e0;
    for (; e + 1 < e1; e += 2) {
        int s0 = csrs[e];
        int s1 = csrs[e + 1];
        float w0 = dinv[s0] * dn;
        float w1 = dinv[s1] * dn;
        ushort4 v0 = *(const ushort4*)(hbf + (size_t)s0 * 128 + fq);
        ushort4 v1 = *(const ushort4*)(hbf + (size_t)s1 * 128 + fq);
        a0 = fmaf(bf2f(v0.x), w0, a0);
        a1 = fmaf(bf2f(v0.y), w0, a1);
        a2 = fmaf(bf2f(v0.z), w0, a2);
        a3 = fmaf(bf2f(v0.w), w0, a3);
        a0 = fmaf(bf2f(v1.x), w1, a0);
        a1 = fmaf(bf2f(v1.y), w1, a1);
        a2 = fmaf(bf2f(v1.z), w1, a2);
        a3 = fmaf(bf2f(v1.w), w1, a3);
    }
    if (e < e1) {
        int s0 = csrs[e];
        float w0 = dinv[s0] * dn;
        ushort4 v0 = *(const ushort4*)(hbf + (size_t)s0 * 128 + fq);
        a0 = fmaf(bf2f(v0.x), w0, a0);
        a1 = fmaf(bf2f(v0.y), w0, a1);
        a2 = fmaf(bf2f(v0.z), w0, a2);
        a3 = fmaf(bf2f(v0.w), w0, a3);
    }
    float4 bb = *(const float4*)(b1 + fq);
    float4 r;
    r.x = fmaxf(a0 + bb.x, 0.f);
    r.y = fmaxf(a1 + bb.y, 0.f);
    r.z = fmaxf(a2 + bb.z, 0.f);
    r.w = fmaxf(a3 + bb.w, 0.f);
    *(float4*)(h1 + (size_t)node * 128 + fq) = r;
}

// ---------------- GEMM2: h2 = h1 @ W2 ([N,128]@[128,40]) -> bf16 ----------------
__global__ __launch_bounds__(64) void k_gemm2(const float* __restrict__ h1,
                                              const float* __restrict__ w2,
                                              u16* __restrict__ h2, int n) {
    __shared__ float hs[64 * 132];
    const int t = threadIdx.x;
    const int n0 = blockIdx.x * 64;
    const float* src = h1 + (size_t)n0 * 128;
#pragma unroll
    for (int i = 0; i < 32; ++i) {
        int idx = i * 64 + t;
        int r = idx >> 5, q = idx & 31;
        float4 v = make_float4(0.f, 0.f, 0.f, 0.f);
        if (n0 + r < n) v = *(const float4*)(src + (size_t)r * 128 + 4 * q);
        *(float4*)&hs[r * 132 + 4 * q] = v;
    }
    __syncthreads();

    float acc[40];
#pragma unroll
    for (int c = 0; c < 40; ++c) acc[c] = 0.f;

    for (int k4 = 0; k4 < 32; ++k4) {
        float4 hv = *(const float4*)&hs[t * 132 + 4 * k4];
#pragma unroll
        for (int j = 0; j < 4; ++j) {
            float xv = (j == 0) ? hv.x : (j == 1) ? hv.y : (j == 2) ? hv.z : hv.w;
            const float* wr = w2 + (size_t)(4 * k4 + j) * 40;
#pragma unroll
            for (int c = 0; c < 40; ++c) acc[c] = fmaf(xv, wr[c], acc[c]);
        }
    }
    __syncthreads();
    u16* hsu = (u16*)&hs[0];
#pragma unroll
    for (int c = 0; c < 40; ++c) hsu[t * 40 + c] = bfbits(acc[c]);
    __syncthreads();
    const int lim = (n - n0 < 64 ? n - n0 : 64) * 40;
    u16* dst = h2 + (size_t)n0 * 40;
#pragma unroll
    for (int i = 0; i < 10; ++i) {
        int idx4 = i * 64 + t;
        if (idx4 * 4 < lim) {
            ushort4 v = ((const ushort4*)hsu)[idx4];
            *(ushort4*)(dst + idx4 * 4) = v;
        }
    }
}

// ---------------- Agg2 + bias + log_softmax fused ----------------
__global__ __launch_bounds__(256) void k_agg2(const u16* __restrict__ h2,
                                              const int* __restrict__ off,
                                              const int* __restrict__ csrs,
                                              const float* __restrict__ dinv,
                                              const float* __restrict__ b2,
                                              float* __restrict__ out, int n) {
    const int t = threadIdx.x;
    const int node = blockIdx.x * 4 + (t >> 6);
    if (node >= n) return;
    const int f = t & 63;
    const float dn = dinv[node];
    float acc = 0.f;
    const int e0 = off[node], e1 = off[node + 1];
    if (f < 40) {
        int e = e0;
        for (; e + 1 < e1; e += 2) {
            int s0 = csrs[e];
            int s1 = csrs[e + 1];
            float w0 = dinv[s0] * dn;
            float w1 = dinv[s1] * dn;
            acc = fmaf(bf2f(h2[(size_t)s0 * 40 + f]), w0, acc);
            acc = fmaf(bf2f(h2[(size_t)s1 * 40 + f]), w1, acc);
        }
        if (e < e1) {
            int s0 = csrs[e];
            acc = fmaf(bf2f(h2[(size_t)s0 * 40 + f]), dinv[s0] * dn, acc);
        }
    }
    float v = (f < 40) ? acc + b2[f] : -INFINITY;
    float m = v;
#pragma unroll
    for (int d = 32; d > 0; d >>= 1) m = fmaxf(m, __shfl_xor(m, d, 64));
    float ev = (f < 40) ? __expf(v - m) : 0.f;
    float s = ev;
#pragma unroll
    for (int d = 32; d > 0; d >>= 1) s += __shfl_xor(s, d, 64);
    if (f < 40) out[(size_t)node * 40 + f] = v - m - logf(s);
}

extern "C" void kernel_launch(void* const* d_in, const int* in_sizes, int n_in,
                              void* d_out, int out_size, void* d_ws, size_t ws_size,
                              hipStream_t stream) {
    const float* x = (const float*)d_in[0];
    const int* ei = (const int*)d_in[1];        // int32 per harness convention
    const float* w1 = (const float*)d_in[2];
    const float* b1 = (const float*)d_in[3];
    const float* w2 = (const float*)d_in[4];
    const float* b2 = (const float*)d_in[5];
    float* out = (float*)d_out;

    const int N = in_sizes[0] / 256;
    const int E = in_sizes[1] / 2;
    const int NB = (N + BN - 1) / BN;

    char* p = (char*)d_ws;
    auto alloc = [&](size_t bytes) {
        char* r = p;
        p += (bytes + 255) & ~(size_t)255;
        return r;
    };
    int* gcnt = (int*)alloc((size_t)NB * 4);
    int* ebase = (int*)alloc((size_t)(NB + 1) * 4);
    int* cursor = (int*)alloc((size_t)NB * 4);
    int* off = (int*)alloc((size_t)(N + 1) * 4);
    float* dinv = (float*)alloc((size_t)N * 4);
    int* csrs = (int*)alloc((size_t)(E + N) * 4);
    short* w1bf = (short*)alloc(32768 * 2);
    u16* hbf = (u16*)alloc((size_t)N * 128 * 2);
    float* h1 = (float*)alloc((size_t)N * 128 * 4);
    u32* staging = (u32*)h1;   // staging dead before agg1 writes h1
    u16* h2 = hbf;             // hbf dead after agg1

    const int nblk = (E + EPB - 1) / EPB;

    hipMemsetAsync(gcnt, 0, (size_t)NB * 4, stream);
    k_cnt<<<nblk, 256, 0, stream>>>(ei + E, gcnt, E, N, NB);
    k_bscan<<<1, 512, 0, stream>>>(gcnt, ebase, cursor, off, NB, N);
    k_scat<<<nblk, 256, 0, stream>>>(ei, cursor, staging, E, N, NB);
    k_build<<<NB, 256, 0, stream>>>(staging, ebase, csrs, off, dinv, N);
    k_w1bf<<<128, 256, 0, stream>>>(w1, w1bf);
    k_gemm1<<<(N + 63) / 64, 256, 0, stream>>>(x, w1bf, hbf, N);
    k_agg1<<<(N + 7) / 8, 256, 0, stream>>>(hbf, off, csrs, dinv, b1, h1, N);
    k_gemm2<<<(N + 63) / 64, 64, 0, stream>>>(h1, w2, h2, N);
    k_agg2<<<(N + 3) / 4, 256, 0, stream>>>(h2, off, csrs, dinv, b2, out, N);
}

// Round 5
// 282.457 us; speedup vs baseline: 1.8869x; 1.2394x over previous
//
#include <hip/hip_runtime.h>
#include <hip/hip_bf16.h>
#include <math.h>
#include <stdint.h>

typedef unsigned short u16;
typedef unsigned int u32;
typedef __attribute__((ext_vector_type(8))) short short8;
typedef __attribute__((ext_vector_type(4))) float f32x4;

#define BN 256      // nodes per bucket (power of 2)
#define NBMAX 400   // max buckets (N<=102400)
#define EPB 4096    // edges per block in count/scatter
#define ST1 160     // staged edges per node, agg1
#define ST2 192     // staged edges per node, agg2

__device__ __forceinline__ u16 bfbits(float f) {
    __hip_bfloat16 h = __float2bfloat16(f);   // RNE; pairs fuse to v_cvt_pk_bf16_f32
    return *reinterpret_cast<u16*>(&h);
}
__device__ __forceinline__ float bf2f(u16 b) {
    return __uint_as_float((uint32_t)b << 16);
}
__device__ __forceinline__ float bflo(u32 v) { return __uint_as_float(v << 16); }
__device__ __forceinline__ float bfhi(u32 v) { return __uint_as_float(v & 0xffff0000u); }

// ---------------- bucket counts (block-aggregated) ----------------
__global__ __launch_bounds__(256) void k_cnt(const int* __restrict__ col,
                                             int* __restrict__ gcnt, int E, int n, int nb) {
    __shared__ int sh[NBMAX];
    const int t = threadIdx.x;
    for (int i = t; i < nb; i += 256) sh[i] = 0;
    __syncthreads();
    const int base = blockIdx.x * EPB;
#pragma unroll
    for (int j = 0; j < 16; ++j) {
        int e = base + j * 256 + t;
        if (e < E) {
            unsigned c = (unsigned)col[e];
            if (c < (unsigned)n) atomicAdd(&sh[c >> 8], 1);
        }
    }
    __syncthreads();
    for (int i = t; i < nb; i += 256)
        if (sh[i]) atomicAdd(&gcnt[i], sh[i]);
}

// ---------------- bucket scan (single block) ----------------
__global__ __launch_bounds__(512) void k_bscan(const int* __restrict__ gcnt,
                                               int* __restrict__ ebase, int* __restrict__ cursor,
                                               int* __restrict__ off, int nb, int n) {
    __shared__ int sh[512];
    const int t = threadIdx.x;
    int v = (t < nb) ? gcnt[t] : 0;
    sh[t] = v;
    __syncthreads();
    for (int d = 1; d < 512; d <<= 1) {
        int x = (t >= d) ? sh[t - d] : 0;
        __syncthreads();
        sh[t] += x;
        __syncthreads();
    }
    if (t < nb) {
        int excl = sh[t] - v;
        ebase[t] = excl;
        cursor[t] = excl;
    }
    if (t == 0) {
        ebase[nb] = sh[511];        // total (valid) edges
        off[n] = sh[511] + n;       // csr total incl. self-loops
    }
}

// ---------------- scatter edges to bucket-contiguous staging ----------------
// staging word: src (17 bits) | c_local (8 bits) << 17
__global__ __launch_bounds__(256) void k_scat(const int* __restrict__ ei,
                                              int* __restrict__ cursor,
                                              u32* __restrict__ staging, int E, int n, int nb) {
    __shared__ int cnt[NBMAX];
    __shared__ int cbase[NBMAX];
    const int t = threadIdx.x;
    for (int i = t; i < nb; i += 256) cnt[i] = 0;
    __syncthreads();
    const int base = blockIdx.x * EPB;
    int rr[16], cc[16], rk[16];
#pragma unroll
    for (int j = 0; j < 16; ++j) {
        int e = base + j * 256 + t;
        cc[j] = -1;
        if (e < E) {
            unsigned r = (unsigned)ei[e], c = (unsigned)ei[E + e];
            if (r < (unsigned)n && c < (unsigned)n) {
                rr[j] = (int)r;
                cc[j] = (int)c;
                rk[j] = atomicAdd(&cnt[c >> 8], 1);
            }
        }
    }
    __syncthreads();
    for (int i = t; i < nb; i += 256)
        if (cnt[i]) cbase[i] = atomicAdd(&cursor[i], cnt[i]);
    __syncthreads();
#pragma unroll
    for (int j = 0; j < 16; ++j) {
        if (cc[j] >= 0) {
            int b = cc[j] >> 8;
            staging[cbase[b] + rk[j]] = (u32)rr[j] | ((u32)(cc[j] & (BN - 1)) << 17);
        }
    }
}

// ---------------- per-bucket CSR build: deg, dinv, off, csrs ----------------
__global__ __launch_bounds__(256) void k_build(const u32* __restrict__ staging,
                                               const int* __restrict__ ebase,
                                               int* __restrict__ csrs, int* __restrict__ off,
                                               float* __restrict__ dinv, int n) {
    __shared__ int sh[256];
    __shared__ int cur[256];
    const int t = threadIdx.x;
    const int b = blockIdx.x;
    const int e0 = ebase[b], e1 = ebase[b + 1];
    const int node0 = b * BN;
    const int nn = min(BN, n - node0);
    sh[t] = 0;
    __syncthreads();
    for (int i = e0 + t; i < e1; i += 256)
        atomicAdd(&sh[staging[i] >> 17], 1);
    __syncthreads();
    const int mycnt = sh[t];
    const int myval = (t < nn) ? mycnt + 1 : 0;   // +1 self-loop
    sh[t] = myval;
    __syncthreads();
    for (int d = 1; d < 256; d <<= 1) {
        int x = (t >= d) ? sh[t - d] : 0;
        __syncthreads();
        sh[t] += x;
        __syncthreads();
    }
    const int excl = sh[t] - myval;
    const int csrbase = e0 + node0;               // edges-before + selfloops-before
    if (t < nn) {
        int node = node0 + t;
        int o = csrbase + excl;
        off[node] = o;
        dinv[node] = rsqrtf((float)(mycnt + 1));
        csrs[o] = node;                           // self-loop first in segment
        cur[t] = o + 1;
    }
    __syncthreads();
    for (int i = e0 + t; i < e1; i += 256) {
        u32 v = staging[i];
        int p = atomicAdd(&cur[v >> 17], 1);
        csrs[p] = (int)(v & 0x1FFFF);
    }
}

// ---------------- W1 -> bf16, pre-swizzled into B-fragment order ----------------
__global__ void k_w1bf(const float* __restrict__ w1, short* __restrict__ w1bf) {
    int i = blockIdx.x * 256 + threadIdx.x;    // 32768 total
    int e = i & 7, l = (i >> 3) & 63, kt = (i >> 9) & 7, ct = i >> 12;
    int k = kt * 32 + (l >> 4) * 8 + e;
    int c = ct * 16 + (l & 15);
    w1bf[i] = (short)bfbits(w1[(size_t)k * 128 + c]);
}

// ---------------- GEMM1 (MFMA bf16): h = x @ W1 -> bf16 ----------------
__global__ __launch_bounds__(256) void k_gemm1(const float* __restrict__ x,
                                               const short* __restrict__ w1bf,
                                               u16* __restrict__ hbf, int n) {
    const int tid = threadIdx.x;
    const int wv = tid >> 6, l = tid & 63;
    const int mrow = wv >> 1, mcol = wv & 1;
    const int lr = l & 15, kg = l >> 4;
    const int n0 = blockIdx.x * 64;

    f32x4 zero = {0.f, 0.f, 0.f, 0.f};
    f32x4 acc[2][4];
#pragma unroll
    for (int m = 0; m < 2; ++m)
#pragma unroll
        for (int c = 0; c < 4; ++c) acc[m][c] = zero;

    const float* xp[2];
#pragma unroll
    for (int m = 0; m < 2; ++m) {
        int row = n0 + 32 * mrow + 16 * m + lr;
        if (row > n - 1) row = n - 1;
        xp[m] = x + (size_t)row * 256 + kg * 8;
    }
    const short* bbase = w1bf + ((size_t)(4 * mcol) * 8) * 64 * 8 + (size_t)l * 8;

#pragma unroll 2
    for (int kt = 0; kt < 8; ++kt) {
        short8 afrag[2];
#pragma unroll
        for (int m = 0; m < 2; ++m) {
            float4 u = *(const float4*)(xp[m] + kt * 32);
            float4 v = *(const float4*)(xp[m] + kt * 32 + 4);
            short8 a;
            a[0] = (short)bfbits(u.x);
            a[1] = (short)bfbits(u.y);
            a[2] = (short)bfbits(u.z);
            a[3] = (short)bfbits(u.w);
            a[4] = (short)bfbits(v.x);
            a[5] = (short)bfbits(v.y);
            a[6] = (short)bfbits(v.z);
            a[7] = (short)bfbits(v.w);
            afrag[m] = a;
        }
#pragma unroll
        for (int c = 0; c < 4; ++c) {
            short8 bfrag = *(const short8*)(bbase + ((size_t)(c * 8 + kt) * 64) * 8);
#pragma unroll
            for (int m = 0; m < 2; ++m)
                acc[m][c] = __builtin_amdgcn_mfma_f32_16x16x32_bf16(afrag[m], bfrag,
                                                                    acc[m][c], 0, 0, 0);
        }
    }

#pragma unroll
    for (int m = 0; m < 2; ++m) {
        int rbase = n0 + 32 * mrow + 16 * m + kg * 4;
#pragma unroll
        for (int r = 0; r < 4; ++r) {
            int row = rbase + r;
            if (row < n) {
#pragma unroll
                for (int c = 0; c < 4; ++c) {
                    int col = 64 * mcol + 16 * c + lr;
                    hbf[(size_t)row * 128 + col] = bfbits(acc[m][c][r]);
                }
            }
        }
    }
}

// ---------------- Agg1: h1 = relu(segsum(h[src]*w)+b1) -> bf16 packed ----------------
// node per wave64; lane = feature pair (u32 load); LDS-staged (src,w); unroll 4.
__global__ __launch_bounds__(256) void k_agg1(const u16* __restrict__ hbf,
                                              const int* __restrict__ off,
                                              const int* __restrict__ csrs,
                                              const float* __restrict__ dinv,
                                              const float* __restrict__ b1,
                                              u16* __restrict__ h1b, int n) {
    __shared__ int s_s[4][ST1];
    __shared__ float s_f[4][ST1];
    const int t = threadIdx.x, wv = t >> 6, l = t & 63;
    const int node = blockIdx.x * 4 + wv;
    const int nd = node < n ? node : n - 1;
    const float dn = dinv[nd];
    const int e0 = off[nd], e1 = off[nd + 1];
    const int deg = e1 - e0;
    const int nst = deg < ST1 ? deg : ST1;
    for (int i = l; i < nst; i += 64) {
        int s = csrs[e0 + i];
        s_s[wv][i] = s;
        s_f[wv][i] = dinv[s] * dn;
    }
    __syncthreads();

    const u32* hb = (const u32*)hbf;     // row stride 64 u32
    float a0 = 0.f, a1 = 0.f;
    int i = 0;
    for (; i + 4 <= nst; i += 4) {
        int s0 = s_s[wv][i], s1 = s_s[wv][i + 1], s2 = s_s[wv][i + 2], s3 = s_s[wv][i + 3];
        float w0 = s_f[wv][i], w1 = s_f[wv][i + 1], w2v = s_f[wv][i + 2], w3 = s_f[wv][i + 3];
        u32 v0 = hb[(size_t)s0 * 64 + l];
        u32 v1 = hb[(size_t)s1 * 64 + l];
        u32 v2 = hb[(size_t)s2 * 64 + l];
        u32 v3 = hb[(size_t)s3 * 64 + l];
        a0 = fmaf(bflo(v0), w0, a0); a1 = fmaf(bfhi(v0), w0, a1);
        a0 = fmaf(bflo(v1), w1, a0); a1 = fmaf(bfhi(v1), w1, a1);
        a0 = fmaf(bflo(v2), w2v, a0); a1 = fmaf(bfhi(v2), w2v, a1);
        a0 = fmaf(bflo(v3), w3, a0); a1 = fmaf(bfhi(v3), w3, a1);
    }
    for (; i < nst; ++i) {
        int s = s_s[wv][i];
        float w = s_f[wv][i];
        u32 v = hb[(size_t)s * 64 + l];
        a0 = fmaf(bflo(v), w, a0); a1 = fmaf(bfhi(v), w, a1);
    }
    for (int j = nst; j < deg; ++j) {     // rare overflow path
        int s = csrs[e0 + j];
        float w = dinv[s] * dn;
        u32 v = hb[(size_t)s * 64 + l];
        a0 = fmaf(bflo(v), w, a0); a1 = fmaf(bfhi(v), w, a1);
    }
    float2 bb = *(const float2*)(b1 + 2 * l);
    float r0 = fmaxf(a0 + bb.x, 0.f);
    float r1 = fmaxf(a1 + bb.y, 0.f);
    if (node < n) {
        u32 o = (u32)bfbits(r0) | ((u32)bfbits(r1) << 16);
        ((u32*)h1b)[(size_t)node * 64 + l] = o;
    }
}

// ---------------- GEMM2: h2 = h1 @ W2 ([N,128]@[128,40]) -> bf16 ----------------
__global__ __launch_bounds__(64) void k_gemm2(const u16* __restrict__ h1b,
                                              const float* __restrict__ w2,
                                              u16* __restrict__ h2, int n) {
    __shared__ float hs[64 * 132];
    const int t = threadIdx.x;
    const int n0 = blockIdx.x * 64;
    const uint4* src = (const uint4*)(h1b + (size_t)n0 * 128);   // 16 uint4 per row
#pragma unroll
    for (int i = 0; i < 16; ++i) {
        int idx = i * 64 + t;
        int r = idx >> 4, q = idx & 15;
        uint4 v = make_uint4(0u, 0u, 0u, 0u);
        if (n0 + r < n) v = src[(size_t)r * 16 + q];
        *(float4*)&hs[r * 132 + q * 8] =
            make_float4(bflo(v.x), bfhi(v.x), bflo(v.y), bfhi(v.y));
        *(float4*)&hs[r * 132 + q * 8 + 4] =
            make_float4(bflo(v.z), bfhi(v.z), bflo(v.w), bfhi(v.w));
    }
    __syncthreads();

    float acc[40];
#pragma unroll
    for (int c = 0; c < 40; ++c) acc[c] = 0.f;

    for (int k4 = 0; k4 < 32; ++k4) {
        float4 hv = *(const float4*)&hs[t * 132 + 4 * k4];
#pragma unroll
        for (int j = 0; j < 4; ++j) {
            float xv = (j == 0) ? hv.x : (j == 1) ? hv.y : (j == 2) ? hv.z : hv.w;
            const float* wr = w2 + (size_t)(4 * k4 + j) * 40;
#pragma unroll
            for (int c = 0; c < 40; ++c) acc[c] = fmaf(xv, wr[c], acc[c]);
        }
    }
    __syncthreads();
    u16* hsu = (u16*)&hs[0];
#pragma unroll
    for (int c = 0; c < 40; ++c) hsu[t * 40 + c] = bfbits(acc[c]);
    __syncthreads();
    const int lim = (n - n0 < 64 ? n - n0 : 64) * 40;
    u16* dst = h2 + (size_t)n0 * 40;
#pragma unroll
    for (int i = 0; i < 10; ++i) {
        int idx4 = i * 64 + t;
        if (idx4 * 4 < lim) {
            ushort4 v = ((const ushort4*)hsu)[idx4];
            *(ushort4*)(dst + idx4 * 4) = v;
        }
    }
}

// ---------------- Agg2 + bias + log_softmax fused ----------------
// node per wave64; 3 edge-groups x 20 lanes (u32 loads); LDS-staged (src,w); unroll 2.
__global__ __launch_bounds__(256) void k_agg2(const u16* __restrict__ h2,
                                              const int* __restrict__ off,
                                              const int* __restrict__ csrs,
                                              const float* __restrict__ dinv,
                                              const float* __restrict__ b2,
                                              float* __restrict__ out, int n) {
    __shared__ int s_s[4][ST2];
    __shared__ float s_f[4][ST2];
    const int t = threadIdx.x, wv = t >> 6, l = t & 63;
    const int node = blockIdx.x * 4 + wv;
    const int nd = node < n ? node : n - 1;
    const float dn = dinv[nd];
    const int e0 = off[nd], e1 = off[nd + 1];
    const int deg = e1 - e0;
    const int nst = deg < ST2 ? deg : ST2;
    for (int i = l; i < nst; i += 64) {
        int s = csrs[e0 + i];
        s_s[wv][i] = s;
        s_f[wv][i] = dinv[s] * dn;
    }
    __syncthreads();

    const int g = (l >= 40) ? 2 : (l >= 20 ? 1 : 0);
    int fl = l - 20 * g;
    if (fl > 19) fl = 19;                 // lanes 60..63 duplicate, result unused
    const u32* hb = (const u32*)h2;       // row stride 20 u32

    float a0 = 0.f, a1 = 0.f;
    int base = 0;
    for (; base + 6 <= nst; base += 6) {
        int eA = base + g, eB = base + 3 + g;
        int sA = s_s[wv][eA], sB = s_s[wv][eB];
        float wA = s_f[wv][eA], wB = s_f[wv][eB];
        u32 vA = hb[(size_t)sA * 20 + fl];
        u32 vB = hb[(size_t)sB * 20 + fl];
        a0 = fmaf(bflo(vA), wA, a0); a1 = fmaf(bfhi(vA), wA, a1);
        a0 = fmaf(bflo(vB), wB, a0); a1 = fmaf(bfhi(vB), wB, a1);
    }
    for (; base < nst; base += 3) {
        int e = base + g;
        bool ok = e < nst;
        int s = ok ? s_s[wv][e] : nd;
        float w = ok ? s_f[wv][e] : 0.f;
        u32 v = hb[(size_t)s * 20 + fl];
        a0 = fmaf(bflo(v), w, a0); a1 = fmaf(bfhi(v), w, a1);
    }
    for (int j = nst; j < deg; j += 3) {  // rare overflow path
        int e = j + g;
        bool ok = e < deg;
        int s = ok ? csrs[e0 + e] : nd;
        float w = ok ? dinv[s] * dn : 0.f;
        u32 v = hb[(size_t)s * 20 + fl];
        a0 = fmaf(bflo(v), w, a0); a1 = fmaf(bfhi(v), w, a1);
    }

    // combine the 3 group partials into lanes 0..19
    float p0 = __shfl(a0, (l + 20) & 63, 64);
    float q0 = __shfl(a0, (l + 40) & 63, 64);
    float p1 = __shfl(a1, (l + 20) & 63, 64);
    float q1 = __shfl(a1, (l + 40) & 63, 64);
    float2 bb = *(const float2*)(b2 + 2 * fl);
    float v0 = a0 + p0 + q0 + bb.x;
    float v1 = a1 + p1 + q1 + bb.y;

    const bool act = (l < 20);
    float m = act ? fmaxf(v0, v1) : -INFINITY;
#pragma unroll
    for (int d = 16; d > 0; d >>= 1) m = fmaxf(m, __shfl_xor(m, d, 32));
    float s = act ? (__expf(v0 - m) + __expf(v1 - m)) : 0.f;
#pragma unroll
    for (int d = 16; d > 0; d >>= 1) s += __shfl_xor(s, d, 32);
    float ls = logf(s);
    if (node < n && act) {
        float2 o = make_float2(v0 - m - ls, v1 - m - ls);
        *(float2*)(out + (size_t)node * 40 + 2 * fl) = o;
    }
}

extern "C" void kernel_launch(void* const* d_in, const int* in_sizes, int n_in,
                              void* d_out, int out_size, void* d_ws, size_t ws_size,
                              hipStream_t stream) {
    const float* x = (const float*)d_in[0];
    const int* ei = (const int*)d_in[1];
    const float* w1 = (const float*)d_in[2];
    const float* b1 = (const float*)d_in[3];
    const float* w2 = (const float*)d_in[4];
    const float* b2 = (const float*)d_in[5];
    float* out = (float*)d_out;

    const int N = in_sizes[0] / 256;
    const int E = in_sizes[1] / 2;
    const int NB = (N + BN - 1) / BN;

    char* p = (char*)d_ws;
    auto alloc = [&](size_t bytes) {
        char* r = p;
        p += (bytes + 255) & ~(size_t)255;
        return r;
    };
    int* gcnt = (int*)alloc((size_t)NB * 4);
    int* ebase = (int*)alloc((size_t)(NB + 1) * 4);
    int* cursor = (int*)alloc((size_t)NB * 4);
    int* off = (int*)alloc((size_t)(N + 1) * 4);
    float* dinv = (float*)alloc((size_t)N * 4);
    int* csrs = (int*)alloc((size_t)(E + N) * 4);
    short* w1bf = (short*)alloc(32768 * 2);
    u16* hbf = (u16*)alloc((size_t)N * 128 * 2);
    u16* h1b = (u16*)alloc((size_t)N * 128 * 2);
    u32* staging = (u32*)h1b;  // staging dead before agg1 writes h1b
    u16* h2 = hbf;             // hbf dead after agg1

    const int nblk = (E + EPB - 1) / EPB;

    hipMemsetAsync(gcnt, 0, (size_t)NB * 4, stream);
    k_cnt<<<nblk, 256, 0, stream>>>(ei + E, gcnt, E, N, NB);
    k_bscan<<<1, 512, 0, stream>>>(gcnt, ebase, cursor, off, NB, N);
    k_scat<<<nblk, 256, 0, stream>>>(ei, cursor, staging, E, N, NB);
    k_build<<<NB, 256, 0, stream>>>(staging, ebase, csrs, off, dinv, N);
    k_w1bf<<<128, 256, 0, stream>>>(w1, w1bf);
    k_gemm1<<<(N + 63) / 64, 256, 0, stream>>>(x, w1bf, hbf, N);
    k_agg1<<<(N + 3) / 4, 256, 0, stream>>>(hbf, off, csrs, dinv, b1, h1b, N);
    k_gemm2<<<(N + 63) / 64, 64, 0, stream>>>(h1b, w2, h2, N);
    k_agg2<<<(N + 3) / 4, 256, 0, stream>>>(h2, off, csrs, dinv, b2, out, N);
}

// Round 6
// 261.504 us; speedup vs baseline: 2.0381x; 1.0801x over previous
//
#include <hip/hip_runtime.h>
#include <hip/hip_bf16.h>
#include <math.h>
#include <stdint.h>

typedef unsigned short u16;
typedef unsigned int u32;
typedef __attribute__((ext_vector_type(8))) short short8;
typedef __attribute__((ext_vector_type(4))) float f32x4;

#define BN 256      // nodes per bucket (power of 2)
#define NBMAX 400   // max buckets (N<=102400)
#define EPB 4096    // edges per block in count/scatter
#define ST1 160     // staged edges per node, agg1
#define ST2 192     // staged edges per node, agg2

__device__ __forceinline__ u16 bfbits(float f) {
    __hip_bfloat16 h = __float2bfloat16(f);   // RNE; pairs fuse to v_cvt_pk_bf16_f32
    return *reinterpret_cast<u16*>(&h);
}
__device__ __forceinline__ float bflo(u32 v) { return __uint_as_float(v << 16); }
__device__ __forceinline__ float bfhi(u32 v) { return __uint_as_float(v & 0xffff0000u); }

// ---------------- bucket counts (block-aggregated) ----------------
__global__ __launch_bounds__(256) void k_cnt(const int* __restrict__ col,
                                             int* __restrict__ gcnt, int E, int n, int nb) {
    __shared__ int sh[NBMAX];
    const int t = threadIdx.x;
    for (int i = t; i < nb; i += 256) sh[i] = 0;
    __syncthreads();
    const int base = blockIdx.x * EPB;
#pragma unroll
    for (int j = 0; j < 16; ++j) {
        int e = base + j * 256 + t;
        if (e < E) {
            unsigned c = (unsigned)col[e];
            if (c < (unsigned)n) atomicAdd(&sh[c >> 8], 1);
        }
    }
    __syncthreads();
    for (int i = t; i < nb; i += 256)
        if (sh[i]) atomicAdd(&gcnt[i], sh[i]);
}

// ---------------- bucket scan (single block) ----------------
__global__ __launch_bounds__(512) void k_bscan(const int* __restrict__ gcnt,
                                               int* __restrict__ ebase, int* __restrict__ cursor,
                                               int* __restrict__ off, int nb, int n) {
    __shared__ int sh[512];
    const int t = threadIdx.x;
    int v = (t < nb) ? gcnt[t] : 0;
    sh[t] = v;
    __syncthreads();
    for (int d = 1; d < 512; d <<= 1) {
        int x = (t >= d) ? sh[t - d] : 0;
        __syncthreads();
        sh[t] += x;
        __syncthreads();
    }
    if (t < nb) {
        int excl = sh[t] - v;
        ebase[t] = excl;
        cursor[t] = excl;
    }
    if (t == 0) {
        ebase[nb] = sh[511];        // total (valid) edges
        off[n] = sh[511] + n;       // csr total incl. self-loops
    }
}

// ---------------- scatter edges to bucket-contiguous staging ----------------
// staging word: src (17 bits) | c_local (8 bits) << 17
__global__ __launch_bounds__(256) void k_scat(const int* __restrict__ ei,
                                              int* __restrict__ cursor,
                                              u32* __restrict__ staging, int E, int n, int nb) {
    __shared__ int cnt[NBMAX];
    __shared__ int cbase[NBMAX];
    const int t = threadIdx.x;
    for (int i = t; i < nb; i += 256) cnt[i] = 0;
    __syncthreads();
    const int base = blockIdx.x * EPB;
    int rr[16], cc[16], rk[16];
#pragma unroll
    for (int j = 0; j < 16; ++j) {
        int e = base + j * 256 + t;
        cc[j] = -1;
        if (e < E) {
            unsigned r = (unsigned)ei[e], c = (unsigned)ei[E + e];
            if (r < (unsigned)n && c < (unsigned)n) {
                rr[j] = (int)r;
                cc[j] = (int)c;
                rk[j] = atomicAdd(&cnt[c >> 8], 1);
            }
        }
    }
    __syncthreads();
    for (int i = t; i < nb; i += 256)
        if (cnt[i]) cbase[i] = atomicAdd(&cursor[i], cnt[i]);
    __syncthreads();
#pragma unroll
    for (int j = 0; j < 16; ++j) {
        if (cc[j] >= 0) {
            int b = cc[j] >> 8;
            staging[cbase[b] + rk[j]] = (u32)rr[j] | ((u32)(cc[j] & (BN - 1)) << 17);
        }
    }
}

// ---------------- per-bucket CSR build: deg, dinv, off, csrs ----------------
__global__ __launch_bounds__(256) void k_build(const u32* __restrict__ staging,
                                               const int* __restrict__ ebase,
                                               int* __restrict__ csrs, int* __restrict__ off,
                                               float* __restrict__ dinv, int n) {
    __shared__ int sh[256];
    __shared__ int cur[256];
    const int t = threadIdx.x;
    const int b = blockIdx.x;
    const int e0 = ebase[b], e1 = ebase[b + 1];
    const int node0 = b * BN;
    const int nn = min(BN, n - node0);
    sh[t] = 0;
    __syncthreads();
    for (int i = e0 + t; i < e1; i += 256)
        atomicAdd(&sh[staging[i] >> 17], 1);
    __syncthreads();
    const int mycnt = sh[t];
    const int myval = (t < nn) ? mycnt + 1 : 0;   // +1 self-loop
    sh[t] = myval;
    __syncthreads();
    for (int d = 1; d < 256; d <<= 1) {
        int x = (t >= d) ? sh[t - d] : 0;
        __syncthreads();
        sh[t] += x;
        __syncthreads();
    }
    const int excl = sh[t] - myval;
    const int csrbase = e0 + node0;               // edges-before + selfloops-before
    if (t < nn) {
        int node = node0 + t;
        int o = csrbase + excl;
        off[node] = o;
        dinv[node] = rsqrtf((float)(mycnt + 1));
        csrs[o] = node;                           // self-loop first in segment
        cur[t] = o + 1;
    }
    __syncthreads();
    for (int i = e0 + t; i < e1; i += 256) {
        u32 v = staging[i];
        int p = atomicAdd(&cur[v >> 17], 1);
        csrs[p] = (int)(v & 0x1FFFF);
    }
}

// ---------------- W1 -> bf16, pre-swizzled into B-fragment order ----------------
__global__ void k_w1bf(const float* __restrict__ w1, short* __restrict__ w1bf) {
    int i = blockIdx.x * 256 + threadIdx.x;    // 32768 total
    int e = i & 7, l = (i >> 3) & 63, kt = (i >> 9) & 7, ct = i >> 12;
    int k = kt * 32 + (l >> 4) * 8 + e;
    int c = ct * 16 + (l & 15);
    w1bf[i] = (short)bfbits(w1[(size_t)k * 128 + c]);
}

// ---------------- permute b1 / W2-rows by sigma: sigma(64a+16c+lr) = 64a+4lr+c ----------------
__device__ __forceinline__ int sigma128(int col) {
    int a = col >> 6, c = (col >> 4) & 3, lr = col & 15;
    return (a << 6) + (lr << 2) + c;
}
__global__ void k_prep(const float* __restrict__ b1, const float* __restrict__ w2,
                       float* __restrict__ b1p, float* __restrict__ w2p) {
    int i = blockIdx.x * 256 + threadIdx.x;
    if (i < 128) b1p[sigma128(i)] = b1[i];
    int j = i - 128;
    if (j >= 0 && j < 128 * 40) {
        int col = j / 40, jj = j - col * 40;
        w2p[sigma128(col) * 40 + jj] = w2[j];
    }
}

// ---------------- GEMM1 (MFMA bf16): h = x @ W1 -> fp8 (sigma-permuted cols) ----------------
// All 32 x-float4 loads issued before compute: latency hidden by MLP, HBM-BW-bound.
__global__ __launch_bounds__(256) void k_gemm1(const float* __restrict__ x,
                                               const short* __restrict__ w1bf,
                                               u32* __restrict__ hbf8, int n) {
    const int tid = threadIdx.x;
    const int wv = tid >> 6, l = tid & 63;
    const int mrow = wv >> 1, mcol = wv & 1;
    const int lr = l & 15, kg = l >> 4;
    const int n0 = blockIdx.x * 64;

    const float* xp[2];
#pragma unroll
    for (int m = 0; m < 2; ++m) {
        int row = n0 + 32 * mrow + 16 * m + lr;
        if (row > n - 1) row = n - 1;
        xp[m] = x + (size_t)row * 256 + kg * 8;
    }
    const short* bbase = w1bf + ((size_t)(4 * mcol) * 8) * 64 * 8 + (size_t)l * 8;

    // ---- phase 1: issue ALL x loads ----
    float4 xv[2][8][2];
#pragma unroll
    for (int kt = 0; kt < 8; ++kt)
#pragma unroll
        for (int m = 0; m < 2; ++m) {
            xv[m][kt][0] = *(const float4*)(xp[m] + kt * 32);
            xv[m][kt][1] = *(const float4*)(xp[m] + kt * 32 + 4);
        }

    // ---- phase 2: convert + MFMA ----
    f32x4 zero = {0.f, 0.f, 0.f, 0.f};
    f32x4 acc[2][4];
#pragma unroll
    for (int m = 0; m < 2; ++m)
#pragma unroll
        for (int c = 0; c < 4; ++c) acc[m][c] = zero;

#pragma unroll
    for (int kt = 0; kt < 8; ++kt) {
        short8 af[2];
#pragma unroll
        for (int m = 0; m < 2; ++m) {
            float4 u = xv[m][kt][0];
            float4 v = xv[m][kt][1];
            short8 a;
            a[0] = (short)bfbits(u.x);
            a[1] = (short)bfbits(u.y);
            a[2] = (short)bfbits(u.z);
            a[3] = (short)bfbits(u.w);
            a[4] = (short)bfbits(v.x);
            a[5] = (short)bfbits(v.y);
            a[6] = (short)bfbits(v.z);
            a[7] = (short)bfbits(v.w);
            af[m] = a;
        }
#pragma unroll
        for (int c = 0; c < 4; ++c) {
            short8 bfrag = *(const short8*)(bbase + ((size_t)(c * 8 + kt) * 64) * 8);
#pragma unroll
            for (int m = 0; m < 2; ++m)
                acc[m][c] = __builtin_amdgcn_mfma_f32_16x16x32_bf16(af[m], bfrag,
                                                                    acc[m][c], 0, 0, 0);
        }
    }

    // epilogue: pack 4 cols (c=0..3) of one row into one fp8 u32; store at sigma order.
    // storage u32 index 16*mcol+lr holds bytes c=0..3 <-> cols 64*mcol+16c+lr. [sigma]
#pragma unroll
    for (int m = 0; m < 2; ++m) {
        int rbase = n0 + 32 * mrow + 16 * m + kg * 4;
#pragma unroll
        for (int r = 0; r < 4; ++r) {
            int row = rbase + r;
            if (row < n) {
                int w = __builtin_amdgcn_cvt_pk_fp8_f32(acc[m][0][r], acc[m][1][r], 0, false);
                w = __builtin_amdgcn_cvt_pk_fp8_f32(acc[m][2][r], acc[m][3][r], w, true);
                hbf8[(size_t)row * 32 + 16 * mcol + lr] = (u32)w;
            }
        }
    }
}

// ---------------- Agg1: h1 = relu(segsum(h8[src]*w)+b1p) -> bf16 packed (sigma order) ----------------
// node per wave64; lane = fp8 feature pair (u16 load, row=128B); LDS-staged (src,w); unroll 4.
__global__ __launch_bounds__(256) void k_agg1(const u32* __restrict__ hbf8,
                                              const int* __restrict__ off,
                                              const int* __restrict__ csrs,
                                              const float* __restrict__ dinv,
                                              const float* __restrict__ b1p,
                                              u16* __restrict__ h1b, int n) {
    __shared__ int s_s[4][ST1];
    __shared__ float s_f[4][ST1];
    const int t = threadIdx.x, wv = t >> 6, l = t & 63;
    const int node = blockIdx.x * 4 + wv;
    const int nd = node < n ? node : n - 1;
    const float dn = dinv[nd];
    const int e0 = off[nd], e1 = off[nd + 1];
    const int deg = e1 - e0;
    const int nst = deg < ST1 ? deg : ST1;
    for (int i = l; i < nst; i += 64) {
        int s = csrs[e0 + i];
        s_s[wv][i] = s;
        s_f[wv][i] = dinv[s] * dn;
    }
    __syncthreads();

    const u16* hb = (const u16*)hbf8;    // row stride 64 u16 (128 fp8)
    float a0 = 0.f, a1 = 0.f;
    int i = 0;
    for (; i + 4 <= nst; i += 4) {
        int s0 = s_s[wv][i], s1 = s_s[wv][i + 1], s2 = s_s[wv][i + 2], s3 = s_s[wv][i + 3];
        float w0 = s_f[wv][i], w1 = s_f[wv][i + 1], w2v = s_f[wv][i + 2], w3 = s_f[wv][i + 3];
        u32 v0 = hb[(size_t)s0 * 64 + l];
        u32 v1 = hb[(size_t)s1 * 64 + l];
        u32 v2 = hb[(size_t)s2 * 64 + l];
        u32 v3 = hb[(size_t)s3 * 64 + l];
        a0 = fmaf(__builtin_amdgcn_cvt_f32_fp8(v0, 0), w0, a0);
        a1 = fmaf(__builtin_amdgcn_cvt_f32_fp8(v0, 1), w0, a1);
        a0 = fmaf(__builtin_amdgcn_cvt_f32_fp8(v1, 0), w1, a0);
        a1 = fmaf(__builtin_amdgcn_cvt_f32_fp8(v1, 1), w1, a1);
        a0 = fmaf(__builtin_amdgcn_cvt_f32_fp8(v2, 0), w2v, a0);
        a1 = fmaf(__builtin_amdgcn_cvt_f32_fp8(v2, 1), w2v, a1);
        a0 = fmaf(__builtin_amdgcn_cvt_f32_fp8(v3, 0), w3, a0);
        a1 = fmaf(__builtin_amdgcn_cvt_f32_fp8(v3, 1), w3, a1);
    }
    for (; i < nst; ++i) {
        int s = s_s[wv][i];
        float w = s_f[wv][i];
        u32 v = hb[(size_t)s * 64 + l];
        a0 = fmaf(__builtin_amdgcn_cvt_f32_fp8(v, 0), w, a0);
        a1 = fmaf(__builtin_amdgcn_cvt_f32_fp8(v, 1), w, a1);
    }
    for (int j = nst; j < deg; ++j) {     // rare overflow path
        int s = csrs[e0 + j];
        float w = dinv[s] * dn;
        u32 v = hb[(size_t)s * 64 + l];
        a0 = fmaf(__builtin_amdgcn_cvt_f32_fp8(v, 0), w, a0);
        a1 = fmaf(__builtin_amdgcn_cvt_f32_fp8(v, 1), w, a1);
    }
    float2 bb = *(const float2*)(b1p + 2 * l);
    float r0 = fmaxf(a0 + bb.x, 0.f);
    float r1 = fmaxf(a1 + bb.y, 0.f);
    if (node < n) {
        u32 o = (u32)bfbits(r0) | ((u32)bfbits(r1) << 16);
        ((u32*)h1b)[(size_t)node * 64 + l] = o;
    }
}

// ---------------- GEMM2: h2 = h1 @ W2p ([N,128]@[128,40]) -> bf16 (true col order) ----------------
__global__ __launch_bounds__(64) void k_gemm2(const u16* __restrict__ h1b,
                                              const float* __restrict__ w2p,
                                              u16* __restrict__ h2, int n) {
    __shared__ float hs[64 * 132];
    const int t = threadIdx.x;
    const int n0 = blockIdx.x * 64;
    const uint4* src = (const uint4*)(h1b + (size_t)n0 * 128);   // 16 uint4 per row
#pragma unroll
    for (int i = 0; i < 16; ++i) {
        int idx = i * 64 + t;
        int r = idx >> 4, q = idx & 15;
        uint4 v = make_uint4(0u, 0u, 0u, 0u);
        if (n0 + r < n) v = src[(size_t)r * 16 + q];
        *(float4*)&hs[r * 132 + q * 8] =
            make_float4(bflo(v.x), bfhi(v.x), bflo(v.y), bfhi(v.y));
        *(float4*)&hs[r * 132 + q * 8 + 4] =
            make_float4(bflo(v.z), bfhi(v.z), bflo(v.w), bfhi(v.w));
    }
    __syncthreads();

    float acc[40];
#pragma unroll
    for (int c = 0; c < 40; ++c) acc[c] = 0.f;

    for (int k4 = 0; k4 < 32; ++k4) {
        float4 hv = *(const float4*)&hs[t * 132 + 4 * k4];
#pragma unroll
        for (int j = 0; j < 4; ++j) {
            float xv = (j == 0) ? hv.x : (j == 1) ? hv.y : (j == 2) ? hv.z : hv.w;
            const float* wr = w2p + (size_t)(4 * k4 + j) * 40;
#pragma unroll
            for (int c = 0; c < 40; ++c) acc[c] = fmaf(xv, wr[c], acc[c]);
        }
    }
    __syncthreads();
    u16* hsu = (u16*)&hs[0];
#pragma unroll
    for (int c = 0; c < 40; ++c) hsu[t * 40 + c] = bfbits(acc[c]);
    __syncthreads();
    const int lim = (n - n0 < 64 ? n - n0 : 64) * 40;
    u16* dst = h2 + (size_t)n0 * 40;
#pragma unroll
    for (int i = 0; i < 10; ++i) {
        int idx4 = i * 64 + t;
        if (idx4 * 4 < lim) {
            ushort4 v = ((const ushort4*)hsu)[idx4];
            *(ushort4*)(dst + idx4 * 4) = v;
        }
    }
}

// ---------------- Agg2 + bias + log_softmax fused ----------------
__global__ __launch_bounds__(256) void k_agg2(const u16* __restrict__ h2,
                                              const int* __restrict__ off,
                                              const int* __restrict__ csrs,
                                              const float* __restrict__ dinv,
                                              const float* __restrict__ b2,
                                              float* __restrict__ out, int n) {
    __shared__ int s_s[4][ST2];
    __shared__ float s_f[4][ST2];
    const int t = threadIdx.x, wv = t >> 6, l = t & 63;
    const int node = blockIdx.x * 4 + wv;
    const int nd = node < n ? node : n - 1;
    const float dn = dinv[nd];
    const int e0 = off[nd], e1 = off[nd + 1];
    const int deg = e1 - e0;
    const int nst = deg < ST2 ? deg : ST2;
    for (int i = l; i < nst; i += 64) {
        int s = csrs[e0 + i];
        s_s[wv][i] = s;
        s_f[wv][i] = dinv[s] * dn;
    }
    __syncthreads();

    const int g = (l >= 40) ? 2 : (l >= 20 ? 1 : 0);
    int fl = l - 20 * g;
    if (fl > 19) fl = 19;                 // lanes 60..63 duplicate, result unused
    const u32* hb = (const u32*)h2;       // row stride 20 u32

    float a0 = 0.f, a1 = 0.f;
    int base = 0;
    for (; base + 6 <= nst; base += 6) {
        int eA = base + g, eB = base + 3 + g;
        int sA = s_s[wv][eA], sB = s_s[wv][eB];
        float wA = s_f[wv][eA], wB = s_f[wv][eB];
        u32 vA = hb[(size_t)sA * 20 + fl];
        u32 vB = hb[(size_t)sB * 20 + fl];
        a0 = fmaf(bflo(vA), wA, a0); a1 = fmaf(bfhi(vA), wA, a1);
        a0 = fmaf(bflo(vB), wB, a0); a1 = fmaf(bfhi(vB), wB, a1);
    }
    for (; base < nst; base += 3) {
        int e = base + g;
        bool ok = e < nst;
        int s = ok ? s_s[wv][e] : nd;
        float w = ok ? s_f[wv][e] : 0.f;
        u32 v = hb[(size_t)s * 20 + fl];
        a0 = fmaf(bflo(v), w, a0); a1 = fmaf(bfhi(v), w, a1);
    }
    for (int j = nst; j < deg; j += 3) {  // rare overflow path
        int e = j + g;
        bool ok = e < deg;
        int s = ok ? csrs[e0 + e] : nd;
        float w = ok ? dinv[s] * dn : 0.f;
        u32 v = hb[(size_t)s * 20 + fl];
        a0 = fmaf(bflo(v), w, a0); a1 = fmaf(bfhi(v), w, a1);
    }

    // combine the 3 group partials into lanes 0..19
    float p0 = __shfl(a0, (l + 20) & 63, 64);
    float q0 = __shfl(a0, (l + 40) & 63, 64);
    float p1 = __shfl(a1, (l + 20) & 63, 64);
    float q1 = __shfl(a1, (l + 40) & 63, 64);
    float2 bb = *(const float2*)(b2 + 2 * fl);
    float v0 = a0 + p0 + q0 + bb.x;
    float v1 = a1 + p1 + q1 + bb.y;

    const bool act = (l < 20);
    float m = act ? fmaxf(v0, v1) : -INFINITY;
#pragma unroll
    for (int d = 16; d > 0; d >>= 1) m = fmaxf(m, __shfl_xor(m, d, 32));
    float s = act ? (__expf(v0 - m) + __expf(v1 - m)) : 0.f;
#pragma unroll
    for (int d = 16; d > 0; d >>= 1) s += __shfl_xor(s, d, 32);
    float ls = logf(s);
    if (node < n && act) {
        float2 o = make_float2(v0 - m - ls, v1 - m - ls);
        *(float2*)(out + (size_t)node * 40 + 2 * fl) = o;
    }
}

extern "C" void kernel_launch(void* const* d_in, const int* in_sizes, int n_in,
                              void* d_out, int out_size, void* d_ws, size_t ws_size,
                              hipStream_t stream) {
    const float* x = (const float*)d_in[0];
    const int* ei = (const int*)d_in[1];
    const float* w1 = (const float*)d_in[2];
    const float* b1 = (const float*)d_in[3];
    const float* w2 = (const float*)d_in[4];
    const float* b2 = (const float*)d_in[5];
    float* out = (float*)d_out;

    const int N = in_sizes[0] / 256;
    const int E = in_sizes[1] / 2;
    const int NB = (N + BN - 1) / BN;

    char* p = (char*)d_ws;
    auto alloc = [&](size_t bytes) {
        char* r = p;
        p += (bytes + 255) & ~(size_t)255;
        return r;
    };
    int* gcnt = (int*)alloc((size_t)NB * 4);
    int* ebase = (int*)alloc((size_t)(NB + 1) * 4);
    int* cursor = (int*)alloc((size_t)NB * 4);
    int* off = (int*)alloc((size_t)(N + 1) * 4);
    float* dinv = (float*)alloc((size_t)N * 4);
    int* csrs = (int*)alloc((size_t)(E + N) * 4);
    short* w1bf = (short*)alloc(32768 * 2);
    float* b1p = (float*)alloc(128 * 4);
    float* w2p = (float*)alloc(128 * 40 * 4);
    u32* hbf8 = (u32*)alloc((size_t)N * 32 * 4);     // fp8 h, sigma-permuted
    u16* h1b = (u16*)alloc((size_t)N * 128 * 2);
    u32* staging = (u32*)h1b;  // staging dead before agg1 writes h1b
    u16* h2 = (u16*)hbf8;      // hbf8 (12.8MB) dead after agg1; h2 needs 8MB

    const int nblk = (E + EPB - 1) / EPB;

    hipMemsetAsync(gcnt, 0, (size_t)NB * 4, stream);
    k_cnt<<<nblk, 256, 0, stream>>>(ei + E, gcnt, E, N, NB);
    k_bscan<<<1, 512, 0, stream>>>(gcnt, ebase, cursor, off, NB, N);
    k_scat<<<nblk, 256, 0, stream>>>(ei, cursor, staging, E, N, NB);
    k_build<<<NB, 256, 0, stream>>>(staging, ebase, csrs, off, dinv, N);
    k_w1bf<<<128, 256, 0, stream>>>(w1, w1bf);
    k_prep<<<21, 256, 0, stream>>>(b1, w2, b1p, w2p);
    k_gemm1<<<(N + 63) / 64, 256, 0, stream>>>(x, w1bf, hbf8, N);
    k_agg1<<<(N + 3) / 4, 256, 0, stream>>>(hbf8, off, csrs, dinv, b1p, h1b, N);
    k_gemm2<<<(N + 63) / 64, 64, 0, stream>>>(h1b, w2p, h2, N);
    k_agg2<<<(N + 3) / 4, 256, 0, stream>>>(h2, off, csrs, dinv, b2, out, N);
}

// Round 8
// 253.097 us; speedup vs baseline: 2.1058x; 1.0332x over previous
//
#include <hip/hip_runtime.h>
#include <hip/hip_bf16.h>
#include <math.h>
#include <stdint.h>

typedef unsigned short u16;
typedef unsigned int u32;
typedef __attribute__((ext_vector_type(8))) short short8;
typedef __attribute__((ext_vector_type(4))) float f32x4;
typedef __attribute__((ext_vector_type(2))) float f32x2;

#define BN 256      // nodes per bucket (power of 2)
#define NBMAX 400   // max buckets (N<=102400)
#define EPB 4096    // edges per block in count/scatter
#define ST1 160     // staged edges per node, agg1
#define ST2 192     // staged edges per node, agg2

__device__ __forceinline__ u16 bfbits(float f) {
    __hip_bfloat16 h = __float2bfloat16(f);   // RNE; pairs fuse to v_cvt_pk_bf16_f32
    return *reinterpret_cast<u16*>(&h);
}
__device__ __forceinline__ float bflo(u32 v) { return __uint_as_float(v << 16); }
__device__ __forceinline__ float bfhi(u32 v) { return __uint_as_float(v & 0xffff0000u); }

template <bool HI>
__device__ __forceinline__ f32x2 fp8pair(u32 v) {
#if __has_builtin(__builtin_amdgcn_cvt_pk_f32_fp8)
    return __builtin_amdgcn_cvt_pk_f32_fp8(v, HI);   // HI is an immediate
#else
    f32x2 r;
    r.x = __builtin_amdgcn_cvt_f32_fp8(v, HI ? 2 : 0);
    r.y = __builtin_amdgcn_cvt_f32_fp8(v, HI ? 3 : 1);
    return r;
#endif
}

// ---------------- bucket counts (block-aggregated) ----------------
__global__ __launch_bounds__(256) void k_cnt(const int* __restrict__ col,
                                             int* __restrict__ gcnt, int E, int n, int nb) {
    __shared__ int sh[NBMAX];
    const int t = threadIdx.x;
    for (int i = t; i < nb; i += 256) sh[i] = 0;
    __syncthreads();
    const int base = blockIdx.x * EPB;
#pragma unroll
    for (int j = 0; j < 16; ++j) {
        int e = base + j * 256 + t;
        if (e < E) {
            unsigned c = (unsigned)col[e];
            if (c < (unsigned)n) atomicAdd(&sh[c >> 8], 1);
        }
    }
    __syncthreads();
    for (int i = t; i < nb; i += 256)
        if (sh[i]) atomicAdd(&gcnt[i], sh[i]);
}

// ---------------- bucket scan (single block) ----------------
__global__ __launch_bounds__(512) void k_bscan(const int* __restrict__ gcnt,
                                               int* __restrict__ ebase, int* __restrict__ cursor,
                                               int* __restrict__ off, int nb, int n) {
    __shared__ int sh[512];
    const int t = threadIdx.x;
    int v = (t < nb) ? gcnt[t] : 0;
    sh[t] = v;
    __syncthreads();
    for (int d = 1; d < 512; d <<= 1) {
        int x = (t >= d) ? sh[t - d] : 0;
        __syncthreads();
        sh[t] += x;
        __syncthreads();
    }
    if (t < nb) {
        int excl = sh[t] - v;
        ebase[t] = excl;
        cursor[t] = excl;
    }
    if (t == 0) {
        ebase[nb] = sh[511];        // total (valid) edges
        off[n] = sh[511] + n;       // csr total incl. self-loops
    }
}

// ---------------- scatter edges to bucket-contiguous staging ----------------
// staging word: src (17 bits) | c_local (8 bits) << 17
__global__ __launch_bounds__(256) void k_scat(const int* __restrict__ ei,
                                              int* __restrict__ cursor,
                                              u32* __restrict__ staging, int E, int n, int nb) {
    __shared__ int cnt[NBMAX];
    __shared__ int cbase[NBMAX];
    const int t = threadIdx.x;
    for (int i = t; i < nb; i += 256) cnt[i] = 0;
    __syncthreads();
    const int base = blockIdx.x * EPB;
    int rr[16], cc[16], rk[16];
#pragma unroll
    for (int j = 0; j < 16; ++j) {
        int e = base + j * 256 + t;
        cc[j] = -1;
        if (e < E) {
            unsigned r = (unsigned)ei[e], c = (unsigned)ei[E + e];
            if (r < (unsigned)n && c < (unsigned)n) {
                rr[j] = (int)r;
                cc[j] = (int)c;
                rk[j] = atomicAdd(&cnt[c >> 8], 1);
            }
        }
    }
    __syncthreads();
    for (int i = t; i < nb; i += 256)
        if (cnt[i]) cbase[i] = atomicAdd(&cursor[i], cnt[i]);
    __syncthreads();
#pragma unroll
    for (int j = 0; j < 16; ++j) {
        if (cc[j] >= 0) {
            int b = cc[j] >> 8;
            staging[cbase[b] + rk[j]] = (u32)rr[j] | ((u32)(cc[j] & (BN - 1)) << 17);
        }
    }
}

// ---------------- per-bucket CSR build: deg, dinv, off, csrs ----------------
__global__ __launch_bounds__(256) void k_build(const u32* __restrict__ staging,
                                               const int* __restrict__ ebase,
                                               int* __restrict__ csrs, int* __restrict__ off,
                                               float* __restrict__ dinv, int n) {
    __shared__ int sh[256];
    __shared__ int cur[256];
    const int t = threadIdx.x;
    const int b = blockIdx.x;
    const int e0 = ebase[b], e1 = ebase[b + 1];
    const int node0 = b * BN;
    const int nn = min(BN, n - node0);
    sh[t] = 0;
    __syncthreads();
    for (int i = e0 + t; i < e1; i += 256)
        atomicAdd(&sh[staging[i] >> 17], 1);
    __syncthreads();
    const int mycnt = sh[t];
    const int myval = (t < nn) ? mycnt + 1 : 0;   // +1 self-loop
    sh[t] = myval;
    __syncthreads();
    for (int d = 1; d < 256; d <<= 1) {
        int x = (t >= d) ? sh[t - d] : 0;
        __syncthreads();
        sh[t] += x;
        __syncthreads();
    }
    const int excl = sh[t] - myval;
    const int csrbase = e0 + node0;               // edges-before + selfloops-before
    if (t < nn) {
        int node = node0 + t;
        int o = csrbase + excl;
        off[node] = o;
        dinv[node] = rsqrtf((float)(mycnt + 1));
        csrs[o] = node;                           // self-loop first in segment
        cur[t] = o + 1;
    }
    __syncthreads();
    for (int i = e0 + t; i < e1; i += 256) {
        u32 v = staging[i];
        int p = atomicAdd(&cur[v >> 17], 1);
        csrs[p] = (int)(v & 0x1FFFF);
    }
}

// ---------------- W1 -> bf16, pre-swizzled into B-fragment order ----------------
__global__ void k_w1bf(const float* __restrict__ w1, short* __restrict__ w1bf) {
    int i = blockIdx.x * 256 + threadIdx.x;    // 32768 total
    int e = i & 7, l = (i >> 3) & 63, kt = (i >> 9) & 7, ct = i >> 12;
    int k = kt * 32 + (l >> 4) * 8 + e;
    int c = ct * 16 + (l & 15);
    w1bf[i] = (short)bfbits(w1[(size_t)k * 128 + c]);
}

// ---------------- permute b1 / W2-rows by sigma: sigma(64a+16c+lr) = 64a+4lr+c ----------------
__device__ __forceinline__ int sigma128(int col) {
    int a = col >> 6, c = (col >> 4) & 3, lr = col & 15;
    return (a << 6) + (lr << 2) + c;
}
__global__ void k_prep(const float* __restrict__ b1, const float* __restrict__ w2,
                       float* __restrict__ b1p, float* __restrict__ w2p) {
    int i = blockIdx.x * 256 + threadIdx.x;
    if (i < 128) b1p[sigma128(i)] = b1[i];
    int j = i - 128;
    if (j >= 0 && j < 128 * 40) {
        int col = j / 40, jj = j - col * 40;
        w2p[sigma128(col) * 40 + jj] = w2[j];
    }
}

// ---------------- GEMM1 (MFMA bf16): h = x @ W1 -> fp8 (sigma-permuted cols) ----------------
__global__ __launch_bounds__(256) void k_gemm1(const float* __restrict__ x,
                                               const short* __restrict__ w1bf,
                                               u32* __restrict__ hbf8, int n) {
    const int tid = threadIdx.x;
    const int wv = tid >> 6, l = tid & 63;
    const int mrow = wv >> 1, mcol = wv & 1;
    const int lr = l & 15, kg = l >> 4;
    const int n0 = blockIdx.x * 64;

    const float* xp[2];
#pragma unroll
    for (int m = 0; m < 2; ++m) {
        int row = n0 + 32 * mrow + 16 * m + lr;
        if (row > n - 1) row = n - 1;
        xp[m] = x + (size_t)row * 256 + kg * 8;
    }
    const short* bbase = w1bf + ((size_t)(4 * mcol) * 8) * 64 * 8 + (size_t)l * 8;

    // ---- phase 1: issue ALL x loads ----
    float4 xv[2][8][2];
#pragma unroll
    for (int kt = 0; kt < 8; ++kt)
#pragma unroll
        for (int m = 0; m < 2; ++m) {
            xv[m][kt][0] = *(const float4*)(xp[m] + kt * 32);
            xv[m][kt][1] = *(const float4*)(xp[m] + kt * 32 + 4);
        }

    // ---- phase 2: convert + MFMA ----
    f32x4 zero = {0.f, 0.f, 0.f, 0.f};
    f32x4 acc[2][4];
#pragma unroll
    for (int m = 0; m < 2; ++m)
#pragma unroll
        for (int c = 0; c < 4; ++c) acc[m][c] = zero;

#pragma unroll
    for (int kt = 0; kt < 8; ++kt) {
        short8 af[2];
#pragma unroll
        for (int m = 0; m < 2; ++m) {
            float4 u = xv[m][kt][0];
            float4 v = xv[m][kt][1];
            short8 a;
            a[0] = (short)bfbits(u.x);
            a[1] = (short)bfbits(u.y);
            a[2] = (short)bfbits(u.z);
            a[3] = (short)bfbits(u.w);
            a[4] = (short)bfbits(v.x);
            a[5] = (short)bfbits(v.y);
            a[6] = (short)bfbits(v.z);
            a[7] = (short)bfbits(v.w);
            af[m] = a;
        }
#pragma unroll
        for (int c = 0; c < 4; ++c) {
            short8 bfrag = *(const short8*)(bbase + ((size_t)(c * 8 + kt) * 64) * 8);
#pragma unroll
            for (int m = 0; m < 2; ++m)
                acc[m][c] = __builtin_amdgcn_mfma_f32_16x16x32_bf16(af[m], bfrag,
                                                                    acc[m][c], 0, 0, 0);
        }
    }

    // epilogue: pack 4 cols (c=0..3) of one row into one fp8 u32; store at sigma order.
#pragma unroll
    for (int m = 0; m < 2; ++m) {
        int rbase = n0 + 32 * mrow + 16 * m + kg * 4;
#pragma unroll
        for (int r = 0; r < 4; ++r) {
            int row = rbase + r;
            if (row < n) {
                int w = __builtin_amdgcn_cvt_pk_fp8_f32(acc[m][0][r], acc[m][1][r], 0, false);
                w = __builtin_amdgcn_cvt_pk_fp8_f32(acc[m][2][r], acc[m][3][r], w, true);
                hbf8[(size_t)row * 32 + 16 * mcol + lr] = (u32)w;
            }
        }
    }
}

// ---------------- Agg1: 2 nodes/wave, 32 lanes/node, u32 fp8 loads, cvt_pk ----------------
__global__ __launch_bounds__(256) void k_agg1(const u32* __restrict__ hbf8,
                                              const int* __restrict__ off,
                                              const int* __restrict__ csrs,
                                              const float* __restrict__ dinv,
                                              const float* __restrict__ b1p,
                                              u16* __restrict__ h1b, int n) {
    __shared__ int s_s[8][ST1];
    __shared__ float s_f[8][ST1];
    const int t = threadIdx.x, h = t >> 5, fl = t & 31;
    const int node = blockIdx.x * 8 + h;
    const int nd = node < n ? node : n - 1;
    const float dn = dinv[nd];
    const int e0 = off[nd], e1 = off[nd + 1];
    const int deg = e1 - e0;
    const int nst = deg < ST1 ? deg : ST1;
    for (int i = fl; i < nst; i += 32) {
        int s = csrs[e0 + i];
        s_s[h][i] = s;
        s_f[h][i] = dinv[s] * dn;
    }
    __syncthreads();

    // pair-wise (other half of the wave) min/max for uniform loop bounds
    const int onst = __shfl_xor(nst, 32, 64);
    const int nmin = nst < onst ? nst : onst;
    const int nmax = nst > onst ? nst : onst;
    const int odeg = __shfl_xor(deg, 32, 64);
    const int dmax = deg > odeg ? deg : odeg;

    const u32* hb = hbf8;                 // row stride 32 u32 (128 fp8)
    float a0 = 0.f, a1 = 0.f, a2 = 0.f, a3 = 0.f;
    int i = 0;
    for (; i + 4 <= nmin; i += 4) {
        int s0 = s_s[h][i], s1 = s_s[h][i + 1], s2 = s_s[h][i + 2], s3 = s_s[h][i + 3];
        float w0 = s_f[h][i], w1 = s_f[h][i + 1], w2v = s_f[h][i + 2], w3 = s_f[h][i + 3];
        u32 v0 = hb[(size_t)s0 * 32 + fl];
        u32 v1 = hb[(size_t)s1 * 32 + fl];
        u32 v2 = hb[(size_t)s2 * 32 + fl];
        u32 v3 = hb[(size_t)s3 * 32 + fl];
        f32x2 lo, hi;
        lo = fp8pair<false>(v0); hi = fp8pair<true>(v0);
        a0 = fmaf(lo.x, w0, a0); a1 = fmaf(lo.y, w0, a1);
        a2 = fmaf(hi.x, w0, a2); a3 = fmaf(hi.y, w0, a3);
        lo = fp8pair<false>(v1); hi = fp8pair<true>(v1);
        a0 = fmaf(lo.x, w1, a0); a1 = fmaf(lo.y, w1, a1);
        a2 = fmaf(hi.x, w1, a2); a3 = fmaf(hi.y, w1, a3);
        lo = fp8pair<false>(v2); hi = fp8pair<true>(v2);
        a0 = fmaf(lo.x, w2v, a0); a1 = fmaf(lo.y, w2v, a1);
        a2 = fmaf(hi.x, w2v, a2); a3 = fmaf(hi.y, w2v, a3);
        lo = fp8pair<false>(v3); hi = fp8pair<true>(v3);
        a0 = fmaf(lo.x, w3, a0); a1 = fmaf(lo.y, w3, a1);
        a2 = fmaf(hi.x, w3, a2); a3 = fmaf(hi.y, w3, a3);
    }
    for (; i < nmin; ++i) {
        int s = s_s[h][i];
        float w = s_f[h][i];
        u32 v = hb[(size_t)s * 32 + fl];
        f32x2 lo = fp8pair<false>(v), hi = fp8pair<true>(v);
        a0 = fmaf(lo.x, w, a0); a1 = fmaf(lo.y, w, a1);
        a2 = fmaf(hi.x, w, a2); a3 = fmaf(hi.y, w, a3);
    }
    for (; i < nmax; ++i) {               // predicated tail (degree mismatch)
        bool ok = i < nst;
        int s = ok ? s_s[h][i] : nd;
        float w = ok ? s_f[h][i] : 0.f;
        u32 v = hb[(size_t)s * 32 + fl];
        f32x2 lo = fp8pair<false>(v), hi = fp8pair<true>(v);
        a0 = fmaf(lo.x, w, a0); a1 = fmaf(lo.y, w, a1);
        a2 = fmaf(hi.x, w, a2); a3 = fmaf(hi.y, w, a3);
    }
    for (int j = ST1; j < dmax; ++j) {    // rare overflow path
        bool ok = j < deg;
        int s = ok ? csrs[e0 + j] : nd;
        float w = ok ? dinv[s] * dn : 0.f;
        u32 v = hb[(size_t)s * 32 + fl];
        f32x2 lo = fp8pair<false>(v), hi = fp8pair<true>(v);
        a0 = fmaf(lo.x, w, a0); a1 = fmaf(lo.y, w, a1);
        a2 = fmaf(hi.x, w, a2); a3 = fmaf(hi.y, w, a3);
    }

    float4 bb = *(const float4*)(b1p + 4 * fl);
    float r0 = fmaxf(a0 + bb.x, 0.f);
    float r1 = fmaxf(a1 + bb.y, 0.f);
    float r2 = fmaxf(a2 + bb.z, 0.f);
    float r3 = fmaxf(a3 + bb.w, 0.f);
    if (node < n) {
        uint2 o;
        o.x = (u32)bfbits(r0) | ((u32)bfbits(r1) << 16);
        o.y = (u32)bfbits(r2) | ((u32)bfbits(r3) << 16);
        ((uint2*)h1b)[(size_t)node * 32 + fl] = o;
    }
}

// ---------------- GEMM2: h2 = h1 @ W2p ([N,128]@[128,40]) -> bf16 (true col order) ----------------
__global__ __launch_bounds__(64) void k_gemm2(const u16* __restrict__ h1b,
                                              const float* __restrict__ w2p,
                                              u16* __restrict__ h2, int n) {
    __shared__ float hs[64 * 132];
    const int t = threadIdx.x;
    const int n0 = blockIdx.x * 64;
    const uint4* src = (const uint4*)(h1b + (size_t)n0 * 128);   // 16 uint4 per row
#pragma unroll
    for (int i = 0; i < 16; ++i) {
        int idx = i * 64 + t;
        int r = idx >> 4, q = idx & 15;
        uint4 v = make_uint4(0u, 0u, 0u, 0u);
        if (n0 + r < n) v = src[(size_t)r * 16 + q];
        *(float4*)&hs[r * 132 + q * 8] =
            make_float4(bflo(v.x), bfhi(v.x), bflo(v.y), bfhi(v.y));
        *(float4*)&hs[r * 132 + q * 8 + 4] =
            make_float4(bflo(v.z), bfhi(v.z), bflo(v.w), bfhi(v.w));
    }
    __syncthreads();

    float acc[40];
#pragma unroll
    for (int c = 0; c < 40; ++c) acc[c] = 0.f;

    for (int k4 = 0; k4 < 32; ++k4) {
        float4 hv = *(const float4*)&hs[t * 132 + 4 * k4];
#pragma unroll
        for (int j = 0; j < 4; ++j) {
            float xv = (j == 0) ? hv.x : (j == 1) ? hv.y : (j == 2) ? hv.z : hv.w;
            const float* wr = w2p + (size_t)(4 * k4 + j) * 40;
#pragma unroll
            for (int c = 0; c < 40; ++c) acc[c] = fmaf(xv, wr[c], acc[c]);
        }
    }
    __syncthreads();
    u16* hsu = (u16*)&hs[0];
#pragma unroll
    for (int c = 0; c < 40; ++c) hsu[t * 40 + c] = bfbits(acc[c]);
    __syncthreads();
    const int lim = (n - n0 < 64 ? n - n0 : 64) * 40;
    u16* dst = h2 + (size_t)n0 * 40;
#pragma unroll
    for (int i = 0; i < 10; ++i) {
        int idx4 = i * 64 + t;
        if (idx4 * 4 < lim) {
            ushort4 v = ((const ushort4*)hsu)[idx4];
            *(ushort4*)(dst + idx4 * 4) = v;
        }
    }
}

// ---------------- Agg2 + bias + log_softmax fused ----------------
__global__ __launch_bounds__(256) void k_agg2(const u16* __restrict__ h2,
                                              const int* __restrict__ off,
                                              const int* __restrict__ csrs,
                                              const float* __restrict__ dinv,
                                              const float* __restrict__ b2,
                                              float* __restrict__ out, int n) {
    __shared__ int s_s[4][ST2];
    __shared__ float s_f[4][ST2];
    const int t = threadIdx.x, wv = t >> 6, l = t & 63;
    const int node = blockIdx.x * 4 + wv;
    const int nd = node < n ? node : n - 1;
    const float dn = dinv[nd];
    const int e0 = off[nd], e1 = off[nd + 1];
    const int deg = e1 - e0;
    const int nst = deg < ST2 ? deg : ST2;
    for (int i = l; i < nst; i += 64) {
        int s = csrs[e0 + i];
        s_s[wv][i] = s;
        s_f[wv][i] = dinv[s] * dn;
    }
    __syncthreads();

    const int g = (l >= 40) ? 2 : (l >= 20 ? 1 : 0);
    int fl = l - 20 * g;
    if (fl > 19) fl = 19;                 // lanes 60..63 duplicate, result unused
    const u32* hb = (const u32*)h2;       // row stride 20 u32

    float a0 = 0.f, a1 = 0.f;
    int base = 0;
    for (; base + 12 <= nst; base += 12) {
        int eA = base + g, eB = base + 3 + g, eC = base + 6 + g, eD = base + 9 + g;
        int sA = s_s[wv][eA], sB = s_s[wv][eB], sC = s_s[wv][eC], sD = s_s[wv][eD];
        float wA = s_f[wv][eA], wB = s_f[wv][eB], wC = s_f[wv][eC], wD = s_f[wv][eD];
        u32 vA = hb[(size_t)sA * 20 + fl];
        u32 vB = hb[(size_t)sB * 20 + fl];
        u32 vC = hb[(size_t)sC * 20 + fl];
        u32 vD = hb[(size_t)sD * 20 + fl];
        a0 = fmaf(bflo(vA), wA, a0); a1 = fmaf(bfhi(vA), wA, a1);
        a0 = fmaf(bflo(vB), wB, a0); a1 = fmaf(bfhi(vB), wB, a1);
        a0 = fmaf(bflo(vC), wC, a0); a1 = fmaf(bfhi(vC), wC, a1);
        a0 = fmaf(bflo(vD), wD, a0); a1 = fmaf(bfhi(vD), wD, a1);
    }
    for (; base + 6 <= nst; base += 6) {
        int eA = base + g, eB = base + 3 + g;
        int sA = s_s[wv][eA], sB = s_s[wv][eB];
        float wA = s_f[wv][eA], wB = s_f[wv][eB];
        u32 vA = hb[(size_t)sA * 20 + fl];
        u32 vB = hb[(size_t)sB * 20 + fl];
        a0 = fmaf(bflo(vA), wA, a0); a1 = fmaf(bfhi(vA), wA, a1);
        a0 = fmaf(bflo(vB), wB, a0); a1 = fmaf(bfhi(vB), wB, a1);
    }
    for (; base < nst; base += 3) {
        int e = base + g;
        bool ok = e < nst;
        int s = ok ? s_s[wv][e] : nd;
        float w = ok ? s_f[wv][e] : 0.f;
        u32 v = hb[(size_t)s * 20 + fl];
        a0 = fmaf(bflo(v), w, a0); a1 = fmaf(bfhi(v), w, a1);
    }
    for (int j = nst; j < deg; j += 3) {  // rare overflow path
        int e = j + g;
        bool ok = e < deg;
        int s = ok ? csrs[e0 + e] : nd;
        float w = ok ? dinv[s] * dn : 0.f;
        u32 v = hb[(size_t)s * 20 + fl];
        a0 = fmaf(bflo(v), w, a0); a1 = fmaf(bfhi(v), w, a1);
    }

    // combine the 3 group partials into lanes 0..19
    float p0 = __shfl(a0, (l + 20) & 63, 64);
    float q0 = __shfl(a0, (l + 40) & 63, 64);
    float p1 = __shfl(a1, (l + 20) & 63, 64);
    float q1 = __shfl(a1, (l + 40) & 63, 64);
    float2 bb = *(const float2*)(b2 + 2 * fl);
    float v0 = a0 + p0 + q0 + bb.x;
    float v1 = a1 + p1 + q1 + bb.y;

    const bool act = (l < 20);
    float m = act ? fmaxf(v0, v1) : -INFINITY;
#pragma unroll
    for (int d = 16; d > 0; d >>= 1) m = fmaxf(m, __shfl_xor(m, d, 32));
    float s = act ? (__expf(v0 - m) + __expf(v1 - m)) : 0.f;
#pragma unroll
    for (int d = 16; d > 0; d >>= 1) s += __shfl_xor(s, d, 32);
    float ls = logf(s);
    if (node < n && act) {
        float2 o = make_float2(v0 - m - ls, v1 - m - ls);
        *(float2*)(out + (size_t)node * 40 + 2 * fl) = o;
    }
}

extern "C" void kernel_launch(void* const* d_in, const int* in_sizes, int n_in,
                              void* d_out, int out_size, void* d_ws, size_t ws_size,
                              hipStream_t stream) {
    const float* x = (const float*)d_in[0];
    const int* ei = (const int*)d_in[1];
    const float* w1 = (const float*)d_in[2];
    const float* b1 = (const float*)d_in[3];
    const float* w2 = (const float*)d_in[4];
    const float* b2 = (const float*)d_in[5];
    float* out = (float*)d_out;

    const int N = in_sizes[0] / 256;
    const int E = in_sizes[1] / 2;
    const int NB = (N + BN - 1) / BN;

    char* p = (char*)d_ws;
    auto alloc = [&](size_t bytes) {
        char* r = p;
        p += (bytes + 255) & ~(size_t)255;
        return r;
    };
    int* gcnt = (int*)alloc((size_t)NB * 4);
    int* ebase = (int*)alloc((size_t)(NB + 1) * 4);
    int* cursor = (int*)alloc((size_t)NB * 4);
    int* off = (int*)alloc((size_t)(N + 1) * 4);
    float* dinv = (float*)alloc((size_t)N * 4);
    int* csrs = (int*)alloc((size_t)(E + N) * 4);
    short* w1bf = (short*)alloc(32768 * 2);
    float* b1p = (float*)alloc(128 * 4);
    float* w2p = (float*)alloc(128 * 40 * 4);
    u32* hbf8 = (u32*)alloc((size_t)N * 32 * 4);     // fp8 h, sigma-permuted
    u16* h1b = (u16*)alloc((size_t)N * 128 * 2);
    u32* staging = (u32*)h1b;  // staging dead before agg1 writes h1b
    u16* h2 = (u16*)hbf8;      // hbf8 (12.8MB) dead after agg1; h2 needs 8MB

    const int nblk = (E + EPB - 1) / EPB;

    (void)hipMemsetAsync(gcnt, 0, (size_t)NB * 4, stream);
    k_cnt<<<nblk, 256, 0, stream>>>(ei + E, gcnt, E, N, NB);
    k_bscan<<<1, 512, 0, stream>>>(gcnt, ebase, cursor, off, NB, N);
    k_scat<<<nblk, 256, 0, stream>>>(ei, cursor, staging, E, N, NB);
    k_build<<<NB, 256, 0, stream>>>(staging, ebase, csrs, off, dinv, N);
    k_w1bf<<<128, 256, 0, stream>>>(w1, w1bf);
    k_prep<<<21, 256, 0, stream>>>(b1, w2, b1p, w2p);
    k_gemm1<<<(N + 63) / 64, 256, 0, stream>>>(x, w1bf, hbf8, N);
    k_agg1<<<(N + 7) / 8, 256, 0, stream>>>(hbf8, off, csrs, dinv, b1p, h1b, N);
    k_gemm2<<<(N + 63) / 64, 64, 0, stream>>>(h1b, w2p, h2, N);
    k_agg2<<<(N + 3) / 4, 256, 0, stream>>>(h2, off, csrs, dinv, b2, out, N);
}

// Round 9
// 240.490 us; speedup vs baseline: 2.2162x; 1.0524x over previous
//
#include <hip/hip_runtime.h>
#include <hip/hip_bf16.h>
#include <math.h>
#include <stdint.h>

typedef unsigned short u16;
typedef unsigned int u32;
typedef __attribute__((ext_vector_type(8))) short short8;
typedef __attribute__((ext_vector_type(4))) float f32x4;
typedef __attribute__((ext_vector_type(2))) float f32x2;

#define BN 256      // nodes per bucket (power of 2)
#define NBMAX 400   // max buckets (N<=102400)
#define EPB 4096    // edges per block in count/scatter
#define ST1 160     // staged edges per node, agg1
#define ST2 192     // staged edges per node, agg2

__device__ __forceinline__ u16 bfbits(float f) {
    __hip_bfloat16 h = __float2bfloat16(f);
    return *reinterpret_cast<u16*>(&h);
}
__device__ __forceinline__ float bflo(u32 v) { return __uint_as_float(v << 16); }
__device__ __forceinline__ float bfhi(u32 v) { return __uint_as_float(v & 0xffff0000u); }

template <bool HI>
__device__ __forceinline__ f32x2 fp8pair(u32 v) {
#if __has_builtin(__builtin_amdgcn_cvt_pk_f32_fp8)
    return __builtin_amdgcn_cvt_pk_f32_fp8(v, HI);
#else
    f32x2 r;
    r.x = __builtin_amdgcn_cvt_f32_fp8(v, HI ? 2 : 0);
    r.y = __builtin_amdgcn_cvt_f32_fp8(v, HI ? 3 : 1);
    return r;
#endif
}

__device__ __forceinline__ int sigma128(int col) {
    int a = col >> 6, c = (col >> 4) & 3, lr = col & 15;
    return (a << 6) + (lr << 2) + c;
}

// ---------------- FUSED: bucket counts | W1->bf16 swizzle | b1/W2 sigma prep ----------------
__global__ __launch_bounds__(256) void k_pre(const int* __restrict__ ei, int E, int n, int nb,
                                             int nblkc, int* __restrict__ gcnt,
                                             const float* __restrict__ w1, short* __restrict__ w1bf,
                                             const float* __restrict__ b1, const float* __restrict__ w2,
                                             float* __restrict__ b1p, float* __restrict__ w2p) {
    __shared__ int sh[NBMAX];
    const int t = threadIdx.x;
    const int b = blockIdx.x;
    if (b < nblkc) {                           // ---- bucket count ----
        const int* col = ei + E;
        for (int i = t; i < nb; i += 256) sh[i] = 0;
        __syncthreads();
        const int base = b * EPB;
#pragma unroll
        for (int j = 0; j < 16; ++j) {
            int e = base + j * 256 + t;
            if (e < E) {
                unsigned c = (unsigned)col[e];
                if (c < (unsigned)n) atomicAdd(&sh[c >> 8], 1);
            }
        }
        __syncthreads();
        for (int i = t; i < nb; i += 256)
            if (sh[i]) atomicAdd(&gcnt[i], sh[i]);
    } else if (b < nblkc + 128) {              // ---- W1 swizzle (32768 elems) ----
        int i = (b - nblkc) * 256 + t;
        int e = i & 7, l = (i >> 3) & 63, kt = (i >> 9) & 7, ct = i >> 12;
        int k = kt * 32 + (l >> 4) * 8 + e;
        int c = ct * 16 + (l & 15);
        w1bf[i] = (short)bfbits(w1[(size_t)k * 128 + c]);
    } else {                                   // ---- b1/W2 sigma permute ----
        int i = (b - nblkc - 128) * 256 + t;
        if (i < 128) b1p[sigma128(i)] = b1[i];
        int j = i - 128;
        if (j >= 0 && j < 128 * 40) {
            int col = j / 40, jj = j - col * 40;
            w2p[sigma128(col) * 40 + jj] = w2[j];
        }
    }
}

// ---------------- bucket scan (single block) ----------------
__global__ __launch_bounds__(512) void k_bscan(const int* __restrict__ gcnt,
                                               int* __restrict__ ebase, int* __restrict__ cursor,
                                               int* __restrict__ off, int nb, int n) {
    __shared__ int sh[512];
    const int t = threadIdx.x;
    int v = (t < nb) ? gcnt[t] : 0;
    sh[t] = v;
    __syncthreads();
    for (int d = 1; d < 512; d <<= 1) {
        int x = (t >= d) ? sh[t - d] : 0;
        __syncthreads();
        sh[t] += x;
        __syncthreads();
    }
    if (t < nb) {
        int excl = sh[t] - v;
        ebase[t] = excl;
        cursor[t] = excl;
    }
    if (t == 0) {
        ebase[nb] = sh[511];
        off[n] = sh[511] + n;
    }
}

// ---------------- FUSED: edge scatter | GEMM1 (MFMA bf16 -> fp8 sigma) ----------------
__global__ __launch_bounds__(256) void k_scatg1(const int* __restrict__ ei,
                                                int* __restrict__ cursor, u32* __restrict__ staging,
                                                int E, int n, int nb, int nblks,
                                                const float* __restrict__ x,
                                                const short* __restrict__ w1bf,
                                                u32* __restrict__ hbf8) {
    __shared__ int cnt[NBMAX];
    __shared__ int cbase[NBMAX];
    const int t = threadIdx.x;
    if ((int)blockIdx.x < nblks) {             // ---- scat ----
        for (int i = t; i < nb; i += 256) cnt[i] = 0;
        __syncthreads();
        const int base = blockIdx.x * EPB;
        int rr[16], cc[16], rk[16];
#pragma unroll
        for (int j = 0; j < 16; ++j) {
            int e = base + j * 256 + t;
            cc[j] = -1;
            if (e < E) {
                unsigned r = (unsigned)ei[e], c = (unsigned)ei[E + e];
                if (r < (unsigned)n && c < (unsigned)n) {
                    rr[j] = (int)r;
                    cc[j] = (int)c;
                    rk[j] = atomicAdd(&cnt[c >> 8], 1);
                }
            }
        }
        __syncthreads();
        for (int i = t; i < nb; i += 256)
            if (cnt[i]) cbase[i] = atomicAdd(&cursor[i], cnt[i]);
        __syncthreads();
#pragma unroll
        for (int j = 0; j < 16; ++j) {
            if (cc[j] >= 0) {
                int b = cc[j] >> 8;
                staging[cbase[b] + rk[j]] = (u32)rr[j] | ((u32)(cc[j] & (BN - 1)) << 17);
            }
        }
        return;
    }
    // ---- gemm1 ----
    const int bid = blockIdx.x - nblks;
    const int wv = t >> 6, l = t & 63;
    const int mrow = wv >> 1, mcol = wv & 1;
    const int lr = l & 15, kg = l >> 4;
    const int n0 = bid * 64;

    const float* xp[2];
#pragma unroll
    for (int m = 0; m < 2; ++m) {
        int row = n0 + 32 * mrow + 16 * m + lr;
        if (row > n - 1) row = n - 1;
        xp[m] = x + (size_t)row * 256 + kg * 8;
    }
    const short* bbase = w1bf + ((size_t)(4 * mcol) * 8) * 64 * 8 + (size_t)l * 8;

    float4 xv[2][8][2];
#pragma unroll
    for (int kt = 0; kt < 8; ++kt)
#pragma unroll
        for (int m = 0; m < 2; ++m) {
            xv[m][kt][0] = *(const float4*)(xp[m] + kt * 32);
            xv[m][kt][1] = *(const float4*)(xp[m] + kt * 32 + 4);
        }

    f32x4 zero = {0.f, 0.f, 0.f, 0.f};
    f32x4 acc[2][4];
#pragma unroll
    for (int m = 0; m < 2; ++m)
#pragma unroll
        for (int c = 0; c < 4; ++c) acc[m][c] = zero;

#pragma unroll
    for (int kt = 0; kt < 8; ++kt) {
        short8 af[2];
#pragma unroll
        for (int m = 0; m < 2; ++m) {
            float4 u = xv[m][kt][0];
            float4 v = xv[m][kt][1];
            short8 a;
            a[0] = (short)bfbits(u.x);
            a[1] = (short)bfbits(u.y);
            a[2] = (short)bfbits(u.z);
            a[3] = (short)bfbits(u.w);
            a[4] = (short)bfbits(v.x);
            a[5] = (short)bfbits(v.y);
            a[6] = (short)bfbits(v.z);
            a[7] = (short)bfbits(v.w);
            af[m] = a;
        }
#pragma unroll
        for (int c = 0; c < 4; ++c) {
            short8 bfrag = *(const short8*)(bbase + ((size_t)(c * 8 + kt) * 64) * 8);
#pragma unroll
            for (int m = 0; m < 2; ++m)
                acc[m][c] = __builtin_amdgcn_mfma_f32_16x16x32_bf16(af[m], bfrag,
                                                                    acc[m][c], 0, 0, 0);
        }
    }

#pragma unroll
    for (int m = 0; m < 2; ++m) {
        int rbase = n0 + 32 * mrow + 16 * m + kg * 4;
#pragma unroll
        for (int r = 0; r < 4; ++r) {
            int row = rbase + r;
            if (row < n) {
                int w = __builtin_amdgcn_cvt_pk_fp8_f32(acc[m][0][r], acc[m][1][r], 0, false);
                w = __builtin_amdgcn_cvt_pk_fp8_f32(acc[m][2][r], acc[m][3][r], w, true);
                hbf8[(size_t)row * 32 + 16 * mcol + lr] = (u32)w;
            }
        }
    }
}

// ---------------- per-bucket CSR build ----------------
__global__ __launch_bounds__(256) void k_build(const u32* __restrict__ staging,
                                               const int* __restrict__ ebase,
                                               int* __restrict__ csrs, int* __restrict__ off,
                                               float* __restrict__ dinv, int n) {
    __shared__ int sh[256];
    __shared__ int cur[256];
    const int t = threadIdx.x;
    const int b = blockIdx.x;
    const int e0 = ebase[b], e1 = ebase[b + 1];
    const int node0 = b * BN;
    const int nn = min(BN, n - node0);
    sh[t] = 0;
    __syncthreads();
    for (int i = e0 + t; i < e1; i += 256)
        atomicAdd(&sh[staging[i] >> 17], 1);
    __syncthreads();
    const int mycnt = sh[t];
    const int myval = (t < nn) ? mycnt + 1 : 0;
    sh[t] = myval;
    __syncthreads();
    for (int d = 1; d < 256; d <<= 1) {
        int x = (t >= d) ? sh[t - d] : 0;
        __syncthreads();
        sh[t] += x;
        __syncthreads();
    }
    const int excl = sh[t] - myval;
    const int csrbase = e0 + node0;
    if (t < nn) {
        int node = node0 + t;
        int o = csrbase + excl;
        off[node] = o;
        dinv[node] = rsqrtf((float)(mycnt + 1));
        csrs[o] = node;
        cur[t] = o + 1;
    }
    __syncthreads();
    for (int i = e0 + t; i < e1; i += 256) {
        u32 v = staging[i];
        int p = atomicAdd(&cur[v >> 17], 1);
        csrs[p] = (int)(v & 0x1FFFF);
    }
}

// ---------------- Agg1: 2 nodes/wave, 32 lanes/node, u32 fp8 loads, unroll 8 ----------------
__global__ __launch_bounds__(256) void k_agg1(const u32* __restrict__ hbf8,
                                              const int* __restrict__ off,
                                              const int* __restrict__ csrs,
                                              const float* __restrict__ dinv,
                                              const float* __restrict__ b1p,
                                              u16* __restrict__ h1b, int n) {
    __shared__ int s_s[8][ST1];
    __shared__ float s_f[8][ST1];
    const int t = threadIdx.x, h = t >> 5, fl = t & 31;
    const int node = blockIdx.x * 8 + h;
    const int nd = node < n ? node : n - 1;
    const float dn = dinv[nd];
    const int e0 = off[nd], e1 = off[nd + 1];
    const int deg = e1 - e0;
    const int nst = deg < ST1 ? deg : ST1;
    for (int i = fl; i < nst; i += 32) {
        int s = csrs[e0 + i];
        s_s[h][i] = s;
        s_f[h][i] = dinv[s] * dn;
    }
    __syncthreads();

    const int onst = __shfl_xor(nst, 32, 64);
    const int nmin = nst < onst ? nst : onst;
    const int nmax = nst > onst ? nst : onst;
    const int odeg = __shfl_xor(deg, 32, 64);
    const int dmax = deg > odeg ? deg : odeg;

    const u32* hb = hbf8;
    float a0 = 0.f, a1 = 0.f, a2 = 0.f, a3 = 0.f;
    int i = 0;
    for (; i + 8 <= nmin; i += 8) {
        u32 vv[8];
        float ww[8];
#pragma unroll
        for (int k = 0; k < 8; ++k) {
            int s = s_s[h][i + k];
            ww[k] = s_f[h][i + k];
            vv[k] = hb[(size_t)s * 32 + fl];
        }
#pragma unroll
        for (int k = 0; k < 8; ++k) {
            f32x2 lo = fp8pair<false>(vv[k]), hi = fp8pair<true>(vv[k]);
            a0 = fmaf(lo.x, ww[k], a0); a1 = fmaf(lo.y, ww[k], a1);
            a2 = fmaf(hi.x, ww[k], a2); a3 = fmaf(hi.y, ww[k], a3);
        }
    }
    for (; i < nmin; ++i) {
        int s = s_s[h][i];
        float w = s_f[h][i];
        u32 v = hb[(size_t)s * 32 + fl];
        f32x2 lo = fp8pair<false>(v), hi = fp8pair<true>(v);
        a0 = fmaf(lo.x, w, a0); a1 = fmaf(lo.y, w, a1);
        a2 = fmaf(hi.x, w, a2); a3 = fmaf(hi.y, w, a3);
    }
    for (; i < nmax; ++i) {
        bool ok = i < nst;
        int s = ok ? s_s[h][i] : nd;
        float w = ok ? s_f[h][i] : 0.f;
        u32 v = hb[(size_t)s * 32 + fl];
        f32x2 lo = fp8pair<false>(v), hi = fp8pair<true>(v);
        a0 = fmaf(lo.x, w, a0); a1 = fmaf(lo.y, w, a1);
        a2 = fmaf(hi.x, w, a2); a3 = fmaf(hi.y, w, a3);
    }
    for (int j = ST1; j < dmax; ++j) {
        bool ok = j < deg;
        int s = ok ? csrs[e0 + j] : nd;
        float w = ok ? dinv[s] * dn : 0.f;
        u32 v = hb[(size_t)s * 32 + fl];
        f32x2 lo = fp8pair<false>(v), hi = fp8pair<true>(v);
        a0 = fmaf(lo.x, w, a0); a1 = fmaf(lo.y, w, a1);
        a2 = fmaf(hi.x, w, a2); a3 = fmaf(hi.y, w, a3);
    }

    float4 bb = *(const float4*)(b1p + 4 * fl);
    float r0 = fmaxf(a0 + bb.x, 0.f);
    float r1 = fmaxf(a1 + bb.y, 0.f);
    float r2 = fmaxf(a2 + bb.z, 0.f);
    float r3 = fmaxf(a3 + bb.w, 0.f);
    if (node < n) {
        uint2 o;
        o.x = (u32)bfbits(r0) | ((u32)bfbits(r1) << 16);
        o.y = (u32)bfbits(r2) | ((u32)bfbits(r3) << 16);
        ((uint2*)h1b)[(size_t)node * 32 + fl] = o;
    }
}

// ---------------- GEMM2: h2 = h1 @ W2p -> int8 (64B rows) + per-node scale ----------------
__global__ __launch_bounds__(64) void k_gemm2(const u16* __restrict__ h1b,
                                              const float* __restrict__ w2p,
                                              u32* __restrict__ h2q, float* __restrict__ scl,
                                              int n) {
    __shared__ float hs[64 * 132];
    const int t = threadIdx.x;
    const int n0 = blockIdx.x * 64;
    const uint4* src = (const uint4*)(h1b + (size_t)n0 * 128);
#pragma unroll
    for (int i = 0; i < 16; ++i) {
        int idx = i * 64 + t;
        int r = idx >> 4, q = idx & 15;
        uint4 v = make_uint4(0u, 0u, 0u, 0u);
        if (n0 + r < n) v = src[(size_t)r * 16 + q];
        *(float4*)&hs[r * 132 + q * 8] =
            make_float4(bflo(v.x), bfhi(v.x), bflo(v.y), bfhi(v.y));
        *(float4*)&hs[r * 132 + q * 8 + 4] =
            make_float4(bflo(v.z), bfhi(v.z), bflo(v.w), bfhi(v.w));
    }
    __syncthreads();

    float acc[40];
#pragma unroll
    for (int c = 0; c < 40; ++c) acc[c] = 0.f;

    for (int k4 = 0; k4 < 32; ++k4) {
        float4 hv = *(const float4*)&hs[t * 132 + 4 * k4];
#pragma unroll
        for (int j = 0; j < 4; ++j) {
            float xv = (j == 0) ? hv.x : (j == 1) ? hv.y : (j == 2) ? hv.z : hv.w;
            const float* wr = w2p + (size_t)(4 * k4 + j) * 40;
#pragma unroll
            for (int c = 0; c < 40; ++c) acc[c] = fmaf(xv, wr[c], acc[c]);
        }
    }
    __syncthreads();

    // int8 quantize with per-node scale
    float mx = 0.f;
#pragma unroll
    for (int c = 0; c < 40; ++c) mx = fmaxf(mx, fabsf(acc[c]));
    const float qs = mx > 0.f ? 127.f / mx : 0.f;
    u32* rowp = (u32*)hs + t * 16;
#pragma unroll
    for (int j = 0; j < 10; ++j) {
        u32 w = 0;
#pragma unroll
        for (int k = 0; k < 4; ++k) {
            int q = __float2int_rn(acc[4 * j + k] * qs);
            q = q > 127 ? 127 : (q < -127 ? -127 : q);
            w |= ((u32)(q & 255)) << (8 * k);
        }
        rowp[j] = w;
    }
#pragma unroll
    for (int j = 10; j < 16; ++j) rowp[j] = 0;
    __syncthreads();
    const int nrow = (n - n0 < 64) ? n - n0 : 64;
    uint4* dst = (uint4*)(h2q + (size_t)n0 * 16);
    const uint4* s4 = (const uint4*)hs;
#pragma unroll
    for (int i = 0; i < 4; ++i) {
        int idx = i * 64 + t;
        if ((idx >> 2) < nrow) dst[idx] = s4[idx];
    }
    if (t < nrow) scl[n0 + t] = mx * (1.f / 127.f);
}

// ---------------- Agg2 (int8 gather) + bias + log_softmax ----------------
// node per wave64; 6 edge-groups x 10 lanes; scale folded into staged weight.
__global__ __launch_bounds__(256) void k_agg2(const u32* __restrict__ h2q,
                                              const float* __restrict__ scl,
                                              const int* __restrict__ off,
                                              const int* __restrict__ csrs,
                                              const float* __restrict__ dinv,
                                              const float* __restrict__ b2,
                                              float* __restrict__ out, int n) {
    __shared__ int s_s[4][ST2];
    __shared__ float s_f[4][ST2];
    const int t = threadIdx.x, wv = t >> 6, l = t & 63;
    const int node = blockIdx.x * 4 + wv;
    const int nd = node < n ? node : n - 1;
    const float dn = dinv[nd];
    const int e0 = off[nd], e1 = off[nd + 1];
    const int deg = e1 - e0;
    const int nst = deg < ST2 ? deg : ST2;
    for (int i = l; i < nst; i += 64) {
        int s = csrs[e0 + i];
        s_s[wv][i] = s;
        s_f[wv][i] = dinv[s] * dn * scl[s];
    }
    __syncthreads();

    int g = l / 10;
    if (g > 5) g = 5;
    const int fl = l - 10 * g;            // 0..9 active; 10..13 read zero-pad (in-bounds)

#define ACC4(v, w)                                                         \
    {                                                                      \
        a0 = fmaf((float)(int)(signed char)((v) & 0xff), (w), a0);         \
        a1 = fmaf((float)(int)(signed char)(((v) >> 8) & 0xff), (w), a1);  \
        a2 = fmaf((float)(int)(signed char)(((v) >> 16) & 0xff), (w), a2); \
        a3 = fmaf((float)(int)(signed char)((v) >> 24), (w), a3);          \
    }

    float a0 = 0.f, a1 = 0.f, a2 = 0.f, a3 = 0.f;
    int base = 0;
    for (; base + 24 <= nst; base += 24) {
        int eA = base + g, eB = base + 6 + g, eC = base + 12 + g, eD = base + 18 + g;
        int sA = s_s[wv][eA], sB = s_s[wv][eB], sC = s_s[wv][eC], sD = s_s[wv][eD];
        float wA = s_f[wv][eA], wB = s_f[wv][eB], wC = s_f[wv][eC], wD = s_f[wv][eD];
        u32 vA = h2q[(size_t)sA * 16 + fl];
        u32 vB = h2q[(size_t)sB * 16 + fl];
        u32 vC = h2q[(size_t)sC * 16 + fl];
        u32 vD = h2q[(size_t)sD * 16 + fl];
        ACC4(vA, wA); ACC4(vB, wB); ACC4(vC, wC); ACC4(vD, wD);
    }
    for (; base + 12 <= nst; base += 12) {
        int eA = base + g, eB = base + 6 + g;
        int sA = s_s[wv][eA], sB = s_s[wv][eB];
        float wA = s_f[wv][eA], wB = s_f[wv][eB];
        u32 vA = h2q[(size_t)sA * 16 + fl];
        u32 vB = h2q[(size_t)sB * 16 + fl];
        ACC4(vA, wA); ACC4(vB, wB);
    }
    for (; base < nst; base += 6) {
        int e = base + g;
        bool ok = e < nst;
        int s = ok ? s_s[wv][e] : nd;
        float w = ok ? s_f[wv][e] : 0.f;
        u32 v = h2q[(size_t)s * 16 + fl];
        ACC4(v, w);
    }
    for (int j = nst; j < deg; j += 6) {  // rare overflow path
        int e = j + g;
        bool ok = e < deg;
        int s = ok ? csrs[e0 + e] : nd;
        float w = ok ? dinv[s] * dn * scl[s] : 0.f;
        u32 v = h2q[(size_t)s * 16 + fl];
        ACC4(v, w);
    }
#undef ACC4

    // fold 6 groups -> lanes 0..9 (read-before-write shuffle pattern)
    float t0 = __shfl(a0, (l + 30) & 63, 64);
    float t1 = __shfl(a1, (l + 30) & 63, 64);
    float t2 = __shfl(a2, (l + 30) & 63, 64);
    float t3 = __shfl(a3, (l + 30) & 63, 64);
    a0 += t0; a1 += t1; a2 += t2; a3 += t3;
    float p0 = __shfl(a0, (l + 10) & 63, 64), q0 = __shfl(a0, (l + 20) & 63, 64);
    float p1 = __shfl(a1, (l + 10) & 63, 64), q1 = __shfl(a1, (l + 20) & 63, 64);
    float p2 = __shfl(a2, (l + 10) & 63, 64), q2 = __shfl(a2, (l + 20) & 63, 64);
    float p3 = __shfl(a3, (l + 10) & 63, 64), q3 = __shfl(a3, (l + 20) & 63, 64);
    a0 += p0 + q0; a1 += p1 + q1; a2 += p2 + q2; a3 += p3 + q3;

    const bool act = (l < 10);
    float4 bb = *(const float4*)(b2 + 4 * (act ? l : 9));
    float v0 = a0 + bb.x, v1 = a1 + bb.y, v2 = a2 + bb.z, v3 = a3 + bb.w;

    float m = act ? fmaxf(fmaxf(v0, v1), fmaxf(v2, v3)) : -INFINITY;
#pragma unroll
    for (int d = 8; d > 0; d >>= 1) m = fmaxf(m, __shfl_xor(m, d, 16));
    float s = act ? (__expf(v0 - m) + __expf(v1 - m) + __expf(v2 - m) + __expf(v3 - m)) : 0.f;
#pragma unroll
    for (int d = 8; d > 0; d >>= 1) s += __shfl_xor(s, d, 16);
    float ls = logf(s);
    if (node < n && act) {
        float4 o = make_float4(v0 - m - ls, v1 - m - ls, v2 - m - ls, v3 - m - ls);
        *(float4*)(out + (size_t)node * 40 + 4 * l) = o;
    }
}

extern "C" void kernel_launch(void* const* d_in, const int* in_sizes, int n_in,
                              void* d_out, int out_size, void* d_ws, size_t ws_size,
                              hipStream_t stream) {
    const float* x = (const float*)d_in[0];
    const int* ei = (const int*)d_in[1];
    const float* w1 = (const float*)d_in[2];
    const float* b1 = (const float*)d_in[3];
    const float* w2 = (const float*)d_in[4];
    const float* b2 = (const float*)d_in[5];
    float* out = (float*)d_out;

    const int N = in_sizes[0] / 256;
    const int E = in_sizes[1] / 2;
    const int NB = (N + BN - 1) / BN;

    char* p = (char*)d_ws;
    auto alloc = [&](size_t bytes) {
        char* r = p;
        p += (bytes + 255) & ~(size_t)255;
        return r;
    };
    int* gcnt = (int*)alloc((size_t)NB * 4);
    int* ebase = (int*)alloc((size_t)(NB + 1) * 4);
    int* cursor = (int*)alloc((size_t)NB * 4);
    int* off = (int*)alloc((size_t)(N + 1) * 4);
    float* dinv = (float*)alloc((size_t)N * 4);
    float* scl = (float*)alloc((size_t)N * 4);
    int* csrs = (int*)alloc((size_t)(E + N) * 4);
    short* w1bf = (short*)alloc(32768 * 2);
    float* b1p = (float*)alloc(128 * 4);
    float* w2p = (float*)alloc(128 * 40 * 4);
    u32* hbf8 = (u32*)alloc((size_t)N * 32 * 4);     // fp8 h, sigma-permuted (12.8MB)
    u16* h1b = (u16*)alloc((size_t)N * 128 * 2);     // bf16 h1 (25.6MB)
    u32* staging = (u32*)h1b;  // staging dead before agg1 writes h1b
    u32* h2q = hbf8;           // int8 h2 rows (6.4MB) alias hbf8 (dead after agg1)

    const int nblk = (E + EPB - 1) / EPB;
    const int g1blk = (N + 63) / 64;

    (void)hipMemsetAsync(gcnt, 0, (size_t)NB * 4, stream);
    k_pre<<<nblk + 128 + 21, 256, 0, stream>>>(ei, E, N, NB, nblk, gcnt, w1, w1bf,
                                               b1, w2, b1p, w2p);
    k_bscan<<<1, 512, 0, stream>>>(gcnt, ebase, cursor, off, NB, N);
    k_scatg1<<<nblk + g1blk, 256, 0, stream>>>(ei, cursor, staging, E, N, NB, nblk,
                                               x, w1bf, hbf8);
    k_build<<<NB, 256, 0, stream>>>(staging, ebase, csrs, off, dinv, N);
    k_agg1<<<(N + 7) / 8, 256, 0, stream>>>(hbf8, off, csrs, dinv, b1p, h1b, N);
    k_gemm2<<<g1blk, 64, 0, stream>>>(h1b, w2p, h2q, scl, N);
    k_agg2<<<(N + 3) / 4, 256, 0, stream>>>(h2q, scl, off, csrs, dinv, b2, out, N);
}